// Round 2
// baseline (974.689 us; speedup 1.0000x reference)
//
#include <hip/hip_runtime.h>
#include <hip/hip_bf16.h>
#include <cstdint>
#include <cstddef>
#include <type_traits>

// RetNet decoder layer, MI355X/gfx950.
// B=2, T=2048, D=2048, H=8, DK=DV=256, CONV_K=4, CHUNK=64, INTER=2816.
// Workspace budget: exactly 209,715,200 bytes (200 MB) with aggressive
// aliasing; kernel_launch early-exits if ws_size is smaller (diagnostic).

typedef __hip_bfloat16 bf16;
typedef __bf16 bf16x8 __attribute__((ext_vector_type(8)));
typedef float f32x4 __attribute__((ext_vector_type(4)));

#define DEVI __device__ __forceinline__

DEVI float bf2f(bf16 x) { return __bfloat162float(x); }
DEVI bf16 f2bf(float x) { return __float2bfloat16(x); }
DEVI float siluf(float x) { return x / (1.f + __expf(-x)); }

// async global->LDS, 16B per lane; LDS dest = wave-uniform base + lane*16.
#define GLL16(gp, lp)                                                  \
  __builtin_amdgcn_global_load_lds(                                    \
      (__attribute__((address_space(1))) void*)(gp),                   \
      (__attribute__((address_space(3))) void*)(lp), 16, 0, 0)

// ---------------------------------------------------------------- block reduce
DEVI float blockSum256(float v) {
  #pragma unroll
  for (int off = 32; off; off >>= 1) v += __shfl_down(v, off, 64);
  __shared__ float sm[4];
  int lane = threadIdx.x & 63, w = threadIdx.x >> 6;
  if (lane == 0) sm[w] = v;
  __syncthreads();
  return sm[0] + sm[1] + sm[2] + sm[3];
}

// ---------------------------------------------------------------- rmsnorm (D=2048) fp32 -> bf16
__global__ void rmsnorm_k(const float* __restrict__ x, const float* __restrict__ w,
                          bf16* __restrict__ out) {
  long row = blockIdx.x;
  const float* xr = x + row * 2048;
  int i0 = threadIdx.x * 4;
  float4 v0 = *(const float4*)(xr + i0);
  float4 v1 = *(const float4*)(xr + 1024 + i0);
  float ss = v0.x*v0.x + v0.y*v0.y + v0.z*v0.z + v0.w*v0.w
           + v1.x*v1.x + v1.y*v1.y + v1.z*v1.z + v1.w*v1.w;
  ss = blockSum256(ss);
  float s = rsqrtf(ss * (1.f/2048.f) + 1e-5f);
  bf16* orow = out + row * 2048;
  orow[i0+0] = f2bf(v0.x*s*w[i0+0]); orow[i0+1] = f2bf(v0.y*s*w[i0+1]);
  orow[i0+2] = f2bf(v0.z*s*w[i0+2]); orow[i0+3] = f2bf(v0.w*s*w[i0+3]);
  orow[1024+i0+0] = f2bf(v1.x*s*w[1024+i0+0]); orow[1024+i0+1] = f2bf(v1.y*s*w[1024+i0+1]);
  orow[1024+i0+2] = f2bf(v1.z*s*w[1024+i0+2]); orow[1024+i0+3] = f2bf(v1.w*s*w[1024+i0+3]);
}

// ---------------------------------------------------------------- rope table: cos/sin per (t, j<128)
__global__ void rope_init(float2* __restrict__ tab) {
  int t = blockIdx.x, j = threadIdx.x;
  double inv = exp((double)(-j) * (9.210340371976184 / 128.0));  // 10000^(-j/128)
  double ang = fmod((double)t * inv, 6.283185307179586);
  tab[t * 128 + j] = make_float2((float)cos(ang), (float)sin(ang));
}

// ---------------------------------------------------------------- weight transpose fp32(R,C) -> bf16(C,R)
__global__ void transpose_w(const float* __restrict__ in, bf16* __restrict__ out,
                            int R, int C) {
  __shared__ float tile[32][33];
  int bx = blockIdx.x * 32, by = blockIdx.y * 32;
  int tx = threadIdx.x, ty = threadIdx.y;  // 32x8
  #pragma unroll
  for (int i = 0; i < 32; i += 8)
    tile[ty + i][tx] = in[(long)(by + ty + i) * C + bx + tx];
  __syncthreads();
  #pragma unroll
  for (int i = 0; i < 32; i += 8)
    out[(long)(bx + ty + i) * R + by + tx] = f2bf(tile[tx][ty + i]);
}

// ---------------------------------------------------------------- bf16 per-head transpose (bh,2048,256)->(bh,256,2048), optional dkc fold
__global__ void transpose_head(const bf16* __restrict__ in, bf16* __restrict__ out,
                               int withDecay) {
  __shared__ bf16 tile[32][33];
  const int bh = blockIdx.z, hh = bh & 7;
  const float gamma = 1.f - exp2f(-5.f - (float)hh);
  const int t0 = blockIdx.y * 32, d0 = blockIdx.x * 32;
  const int tx = threadIdx.x, ty = threadIdx.y;
  const bf16* src = in + (long)bh * 2048 * 256;
  bf16* dst = out + (long)bh * 2048 * 256;
  #pragma unroll
  for (int i = 0; i < 32; i += 8) {
    int t = t0 + ty + i;
    float v = bf2f(src[(long)t * 256 + d0 + tx]);
    if (withDecay) v *= powf(gamma, (float)(63 - (t & 63)));
    tile[ty + i][tx] = f2bf(v);
  }
  __syncthreads();
  #pragma unroll
  for (int i = 0; i < 32; i += 8)
    dst[(long)(d0 + ty + i) * 2048 + t0 + tx] = tile[tx][ty + i];
}

// ---------------------------------------------------------------- GEMM: C(M,N) = A(M,K)bf16 @ Bt(N,K)bf16 [+ fp32 addend]
template <typename OUT_T, bool DO_ADD>
__global__ __launch_bounds__(256) void gemm_bt(
    const bf16* __restrict__ A, const bf16* __restrict__ Bt,
    OUT_T* __restrict__ C, const float* __restrict__ addend,
    int M, int N, int K) {
  __shared__ alignas(16) bf16 As[128 * 32];
  __shared__ alignas(16) bf16 Bs[128 * 32];
  const int tid = threadIdx.x;
  const int lane = tid & 63, wid = tid >> 6;
  const int quad = lane >> 4, l16 = lane & 15;
  const int wm = wid >> 1, wn = wid & 1;  // 2x2 waves, 64x64 each
  const long bm = (long)blockIdx.x * 128;
  const long bn = (long)blockIdx.y * 128;

  const int srow = wid * 16 + (lane >> 2);   // staging: uniform base + lane*16
  const int scol = (lane & 3) * 8;
  const bf16* pa0 = A + (bm + srow) * (long)K + scol;
  const bf16* pa1 = A + (bm + 64 + srow) * (long)K + scol;
  const bf16* pb0 = Bt + (bn + srow) * (long)K + scol;
  const bf16* pb1 = Bt + (bn + 64 + srow) * (long)K + scol;
  bf16* la0 = As + srow * 32 + scol;
  bf16* la1 = As + (64 + srow) * 32 + scol;
  bf16* lb0 = Bs + srow * 32 + scol;
  bf16* lb1 = Bs + (64 + srow) * 32 + scol;

  const f32x4 zz = {0.f, 0.f, 0.f, 0.f};
  f32x4 acc[4][4];
  #pragma unroll
  for (int i = 0; i < 4; i++)
    #pragma unroll
    for (int j = 0; j < 4; j++) acc[i][j] = zz;

  for (int k0 = 0; k0 < K; k0 += 32) {
    GLL16(pa0 + k0, la0);
    GLL16(pa1 + k0, la1);
    GLL16(pb0 + k0, lb0);
    GLL16(pb1 + k0, lb1);
    __syncthreads();
    bf16x8 a[4], b[4];
    #pragma unroll
    for (int i = 0; i < 4; i++)
      a[i] = *(const bf16x8*)(As + (wm * 64 + i * 16 + l16) * 32 + quad * 8);
    #pragma unroll
    for (int j = 0; j < 4; j++)
      b[j] = *(const bf16x8*)(Bs + (wn * 64 + j * 16 + l16) * 32 + quad * 8);
    #pragma unroll
    for (int i = 0; i < 4; i++)
      #pragma unroll
      for (int j = 0; j < 4; j++)
        acc[i][j] = __builtin_amdgcn_mfma_f32_16x16x32_bf16(a[i], b[j], acc[i][j], 0, 0, 0);
    __syncthreads();
  }

  #pragma unroll
  for (int i = 0; i < 4; i++)
    #pragma unroll
    for (int j = 0; j < 4; j++)
      #pragma unroll
      for (int r = 0; r < 4; r++) {
        long row = bm + wm * 64 + i * 16 + quad * 4 + r;  // C: row=quad*4+r, col=l16
        long col = bn + wn * 64 + j * 16 + l16;
        float v = acc[i][j][r];
        if constexpr (DO_ADD) v += addend[row * (long)N + col];
        if constexpr (std::is_same<OUT_T, float>::value)
          C[row * (long)N + col] = v;
        else
          C[row * (long)N + col] = f2bf(v);
      }
}

// ---------------------------------------------------------------- conv(K=4)+silu (+rope); u is bf16; out (b,h,t,e) bf16
template <bool DO_ROPE>
__global__ void conv_act(const bf16* __restrict__ u, const float* __restrict__ cw,
                         const float2* __restrict__ rtab, bf16* __restrict__ out,
                         float scale) {
  const int bt = blockIdx.x;
  const int t = bt & 2047;
  const int b = bt >> 11;
  const int h = blockIdx.y;
  if constexpr (DO_ROPE) {
    const int j = threadIdx.x;  // 0..127
    const int c1 = h * 256 + j, c2 = c1 + 128;
    float a1 = 0.f, a2 = 0.f;
    #pragma unroll
    for (int i = 0; i < 4; i++) {
      int ts = t - 3 + i;
      if (ts >= 0) {
        const bf16* up = u + (long)(bt - 3 + i) * 2048;
        a1 += bf2f(up[c1]) * cw[c1 * 4 + i];
        a2 += bf2f(up[c2]) * cw[c2 * 4 + i];
      }
    }
    a1 = siluf(a1); a2 = siluf(a2);
    float2 cssn = rtab[t * 128 + j];
    float o1 = (a1 * cssn.x - a2 * cssn.y) * scale;
    float o2 = (a2 * cssn.x + a1 * cssn.y) * scale;
    long base = ((long)(b * 8 + h) * 2048 + t) * 256;
    out[base + j] = f2bf(o1);
    out[base + 128 + j] = f2bf(o2);
  } else {
    const int e = threadIdx.x;  // 0..255
    const int c = h * 256 + e;
    float a = 0.f;
    #pragma unroll
    for (int i = 0; i < 4; i++) {
      int ts = t - 3 + i;
      if (ts >= 0) a += bf2f(u[(long)(bt - 3 + i) * 2048 + c]) * cw[c * 4 + i];
    }
    long base = ((long)(b * 8 + h) * 2048 + t) * 256;
    out[base + e] = f2bf(siluf(a));
  }
}

// ---------------------------------------------------------------- retention A: per (bh,chunk) M^T[e][d] = sum_t v[t,e]*k'[t,d]
__global__ __launch_bounds__(256) void chunk_outer(
    const bf16* __restrict__ vT, const bf16* __restrict__ kTd,
    bf16* __restrict__ states) {
  __shared__ alignas(16) bf16 lk[256 * 72];
  const int chunk = blockIdx.x, bh = blockIdx.y;
  const int tid = threadIdx.x;
  const int lane = tid & 63, wid = tid >> 6;
  const int quad = lane >> 4, l16 = lane & 15;
  const long base = (long)bh * 256 * 2048 + chunk * 64;

  #pragma unroll
  for (int it = 0; it < 8; it++) {
    int r = it * 32 + (tid >> 3);
    int cb = tid & 7;
    *(int4*)(lk + r * 72 + cb * 8) = *(const int4*)(kTd + base + (long)r * 2048 + cb * 8);
  }
  bf16x8 a[4][2];
  #pragma unroll
  for (int i = 0; i < 4; i++)
    #pragma unroll
    for (int ks = 0; ks < 2; ks++)
      a[i][ks] = *(const bf16x8*)(vT + base + (long)(wid * 64 + i * 16 + l16) * 2048 +
                                  ks * 32 + quad * 8);
  __syncthreads();

  bf16* sout = states + ((long)bh * 32 + chunk) * 65536;
  const f32x4 zz = {0.f, 0.f, 0.f, 0.f};
  for (int g = 0; g < 4; g++) {
    f32x4 acc[4][4];
    #pragma unroll
    for (int i = 0; i < 4; i++)
      #pragma unroll
      for (int j = 0; j < 4; j++) acc[i][j] = zz;
    #pragma unroll
    for (int ks = 0; ks < 2; ks++) {
      bf16x8 b[4];
      #pragma unroll
      for (int j = 0; j < 4; j++)
        b[j] = *(const bf16x8*)(lk + (g * 64 + j * 16 + l16) * 72 + ks * 32 + quad * 8);
      #pragma unroll
      for (int i = 0; i < 4; i++)
        #pragma unroll
        for (int j = 0; j < 4; j++)
          acc[i][j] = __builtin_amdgcn_mfma_f32_16x16x32_bf16(a[i][ks], b[j], acc[i][j], 0, 0, 0);
    }
    #pragma unroll
    for (int i = 0; i < 4; i++)
      #pragma unroll
      for (int j = 0; j < 4; j++)
        #pragma unroll
        for (int r = 0; r < 4; r++) {
          int e = wid * 64 + i * 16 + quad * 4 + r;
          int d = g * 64 + j * 16 + l16;
          sout[(long)e * 256 + d] = f2bf(acc[i][j][r]);
        }
  }
}

// ---------------------------------------------------------------- retention B: in-place decay scan (fp32 carry)
__global__ void state_scan(bf16* __restrict__ states) {
  const int bh = blockIdx.y, h = bh & 7;
  const float gamma = 1.f - exp2f(-5.f - (float)h);
  const float gC = powf(gamma, 64.f);
  long idx = (long)blockIdx.x * 256 + threadIdx.x;
  bf16* p = states + (long)bh * 32 * 65536 + idx;
  float s = 0.f;
  for (int n = 0; n < 32; n++) {
    float m = bf2f(p[(long)n * 65536]);
    p[(long)n * 65536] = f2bf(s);
    s = gC * s + m;
  }
}

// ---------------------------------------------------------------- retention C: O = [A*Dm | q*di] @ [v ; S]
__global__ __launch_bounds__(256) void chunk_inner(
    const bf16* __restrict__ q, const bf16* __restrict__ k,
    const bf16* __restrict__ vT, const bf16* __restrict__ ST,
    bf16* __restrict__ o) {
  __shared__ alignas(16) bf16 P[64 * 328];
  const int chunk = blockIdx.x, bh = blockIdx.y;
  const int b_ = bh >> 3, h = bh & 7;
  const float gamma = 1.f - exp2f(-5.f - (float)h);
  const int tid = threadIdx.x;
  const int lane = tid & 63, wid = tid >> 6;
  const int quad = lane >> 4, l16 = lane & 15;
  const long qkbase = ((long)bh * 2048 + chunk * 64) * 256;

  {  // P-right: q * di
    const int row = tid >> 2, cb = tid & 3;
    const float di = powf(gamma, (float)(row + 1));
    const bf16* qs = q + qkbase + (long)row * 256 + cb * 64;
    bf16* pd = P + row * 328 + 64 + cb * 64;
    #pragma unroll
    for (int mb = 0; mb < 8; mb++) {
      bf16x8 v = *(const bf16x8*)(qs + mb * 8);
      #pragma unroll
      for (int e = 0; e < 8; e++) pd[mb * 8 + e] = f2bf((float)v[e] * di);
    }
  }

  {  // A = q k^T with decay mask -> P-left
    const f32x4 zz = {0.f, 0.f, 0.f, 0.f};
    f32x4 acc[4];
    #pragma unroll
    for (int j = 0; j < 4; j++) acc[j] = zz;
    #pragma unroll
    for (int ks = 0; ks < 8; ks++) {
      bf16x8 a = *(const bf16x8*)(q + qkbase + (long)(wid * 16 + l16) * 256 + ks * 32 + quad * 8);
      #pragma unroll
      for (int j = 0; j < 4; j++) {
        bf16x8 b = *(const bf16x8*)(k + qkbase + (long)(j * 16 + l16) * 256 + ks * 32 + quad * 8);
        acc[j] = __builtin_amdgcn_mfma_f32_16x16x32_bf16(a, b, acc[j], 0, 0, 0);
      }
    }
    #pragma unroll
    for (int j = 0; j < 4; j++)
      #pragma unroll
      for (int r = 0; r < 4; r++) {
        int il = wid * 16 + quad * 4 + r;
        int jl = j * 16 + l16;
        int dd = il - jl;
        float v = (dd >= 0) ? acc[j][r] * powf(gamma, (float)dd) : 0.f;
        P[il * 328 + jl] = f2bf(v);
      }
  }
  __syncthreads();

  {  // O = P @ [v ; S]
    const f32x4 zz = {0.f, 0.f, 0.f, 0.f};
    f32x4 acc[4][4];
    #pragma unroll
    for (int i = 0; i < 4; i++)
      #pragma unroll
      for (int j = 0; j < 4; j++) acc[i][j] = zz;
    const long vbase = (long)bh * 256 * 2048 + chunk * 64;
    const long sbase = ((long)bh * 32 + chunk) * 65536;
    #pragma unroll
    for (int ks = 0; ks < 10; ks++) {
      bf16x8 a[4];
      #pragma unroll
      for (int i = 0; i < 4; i++)
        a[i] = *(const bf16x8*)(P + (i * 16 + l16) * 328 + ks * 32 + quad * 8);
      int kk = ks * 32 + quad * 8;
      bf16x8 b[4];
      #pragma unroll
      for (int j = 0; j < 4; j++) {
        int e = wid * 64 + j * 16 + l16;
        const bf16* src = (kk < 64) ? (vT + vbase + (long)e * 2048 + kk)
                                    : (ST + sbase + (long)e * 256 + (kk - 64));
        b[j] = *(const bf16x8*)src;
      }
      #pragma unroll
      for (int i = 0; i < 4; i++)
        #pragma unroll
        for (int j = 0; j < 4; j++)
          acc[i][j] = __builtin_amdgcn_mfma_f32_16x16x32_bf16(a[i], b[j], acc[i][j], 0, 0, 0);
    }
    #pragma unroll
    for (int i = 0; i < 4; i++)
      #pragma unroll
      for (int j = 0; j < 4; j++)
        #pragma unroll
        for (int r = 0; r < 4; r++) {
          int trow = chunk * 64 + i * 16 + quad * 4 + r;
          int e = wid * 64 + j * 16 + l16;
          o[(((long)b_ * 2048 + trow) * 8 + h) * 256 + e] = f2bf(acc[i][j][r]);
        }
  }
}

// ---------------------------------------------------------------- rmsnorm(o)*silu(g) per head -> bf16
__global__ void gated_norm(const bf16* __restrict__ o, const bf16* __restrict__ g,
                           const float* __restrict__ gw, bf16* __restrict__ out) {
  long row = blockIdx.x;
  int e = threadIdx.x;
  float x = bf2f(o[row * 256 + e]);
  float ss = blockSum256(x * x);
  float scale = rsqrtf(ss * (1.f/256.f) + 1e-5f);
  float gg = bf2f(g[row * 256 + e]);
  out[row * 256 + e] = f2bf(x * scale * gw[e] * siluf(gg));
}

// ---------------------------------------------------------------- swiglu
__global__ void swiglu_k(const bf16* __restrict__ gy, bf16* __restrict__ act) {
  long i = (long)blockIdx.x * 256 + threadIdx.x;
  long m = i / 2816, c = i - m * 2816;
  float gv = bf2f(gy[m * 5632 + c]);
  float vv = bf2f(gy[m * 5632 + 2816 + c]);
  act[i] = f2bf(siluf(gv) * vv);
}

// ================================================================ launch
extern "C" void kernel_launch(void* const* d_in, const int* in_sizes, int n_in,
                              void* d_out, int out_size, void* d_ws, size_t ws_size,
                              hipStream_t stream) {
  (void)in_sizes; (void)n_in; (void)out_size;
  const float* hidden = (const float*)d_in[0];
  const float* attn_w = (const float*)d_in[1];
  const float* Wq = (const float*)d_in[2];
  const float* Wk = (const float*)d_in[3];
  const float* Wv = (const float*)d_in[4];
  const float* Wg = (const float*)d_in[5];
  const float* Wo = (const float*)d_in[6];
  const float* cwq = (const float*)d_in[7];
  const float* cwk = (const float*)d_in[8];
  const float* cwv = (const float*)d_in[9];
  const float* gnw = (const float*)d_in[10];
  const float* mlpw = (const float*)d_in[11];
  const float* Wgate = (const float*)d_in[12];
  const float* Wdown = (const float*)d_in[13];
  float* out = (float*)d_out;
  char* ws = (char*)d_ws;

  // ---- workspace layout (200 MB total)
  const size_t MB16 = (size_t)16777216;
  const size_t NEEDED = 209715200ull;
  if (ws_size < NEEDED) return;  // diagnostic guard (same branch every call)

  bf16*  WT   = (bf16*)(ws);                         // 23,068,672 (fits Wgate^T)
  char*  S    = ws + 23068672;                       // 67,108,864 union:
  bf16*  xbf  = (bf16*)(S);                          //   xbf  16.8MB
  float* hbuf = (float*)(S + MB16);                  //   hbuf 33.6MB fp32
  bf16*  u    = (bf16*)(S + MB16 + 2 * MB16);        //   u    16.8MB
  bf16*  states = (bf16*)(S);                        //   states 67.1MB (aliases all 3)
  char*  p    = ws + 23068672 + 67108864;
  bf16*  qb  = (bf16*)(p);              bf16* gy  = qb;   // gy 46.1MB over qb+kb+kTb
  bf16*  kb  = (bf16*)(p + MB16);
  bf16*  kTb = (bf16*)(p + 2 * MB16);
  bf16*  vTb = (bf16*)(p + 3 * MB16);   bf16* act = vTb;  // act 23.1MB over vTb+vnb
  bf16*  vnb = (bf16*)(p + 4 * MB16);   bf16* og  = vnb;
  bf16*  g   = (bf16*)(p + 5 * MB16);
  bf16*  o   = (bf16*)(p + 6 * MB16);   bf16* ybf = o;
  float2* rtab = (float2*)(p + 7 * MB16);            // 2MB

  dim3 tb32(32, 8);

  rope_init<<<2048, 128, 0, stream>>>(rtab);
  rmsnorm_k<<<4096, 256, 0, stream>>>(hidden, attn_w, xbf);

  // q
  transpose_w<<<dim3(64, 64), tb32, 0, stream>>>(Wq, WT, 2048, 2048);
  gemm_bt<bf16, false><<<dim3(32, 16), 256, 0, stream>>>(xbf, WT, u, nullptr, 4096, 2048, 2048);
  conv_act<true><<<dim3(4096, 8), 128, 0, stream>>>(u, cwq, rtab, qb, 0.0625f);  // dk^-0.5 folded
  // k
  transpose_w<<<dim3(64, 64), tb32, 0, stream>>>(Wk, WT, 2048, 2048);
  gemm_bt<bf16, false><<<dim3(32, 16), 256, 0, stream>>>(xbf, WT, u, nullptr, 4096, 2048, 2048);
  conv_act<true><<<dim3(4096, 8), 128, 0, stream>>>(u, cwk, rtab, kb, 1.0f);
  transpose_head<<<dim3(8, 64, 16), tb32, 0, stream>>>(kb, kTb, 1);  // fold dkc
  // v
  transpose_w<<<dim3(64, 64), tb32, 0, stream>>>(Wv, WT, 2048, 2048);
  gemm_bt<bf16, false><<<dim3(32, 16), 256, 0, stream>>>(xbf, WT, u, nullptr, 4096, 2048, 2048);
  conv_act<false><<<dim3(4096, 8), 256, 0, stream>>>(u, cwv, rtab, vnb, 1.0f);
  transpose_head<<<dim3(8, 64, 16), tb32, 0, stream>>>(vnb, vTb, 0);
  // g
  transpose_w<<<dim3(64, 64), tb32, 0, stream>>>(Wg, WT, 2048, 2048);
  gemm_bt<bf16, false><<<dim3(32, 16), 256, 0, stream>>>(xbf, WT, g, nullptr, 4096, 2048, 2048);

  // retention (states overwrite xbf/hbuf/u — all dead or not-yet-live here)
  chunk_outer<<<dim3(32, 16), 256, 0, stream>>>(vTb, kTb, states);
  state_scan<<<dim3(256, 16), 256, 0, stream>>>(states);
  chunk_inner<<<dim3(32, 16), 256, 0, stream>>>(qb, kb, vTb, states, o);

  gated_norm<<<32768, 256, 0, stream>>>(o, g, gnw, og);

  // output projection + residual (states now dead -> hbuf region free)
  transpose_w<<<dim3(64, 64), tb32, 0, stream>>>(Wo, WT, 2048, 2048);
  gemm_bt<float, true><<<dim3(32, 16), 256, 0, stream>>>(og, WT, hbuf, hidden, 4096, 2048, 2048);

  // MLP
  rmsnorm_k<<<4096, 256, 0, stream>>>(hbuf, mlpw, ybf);
  transpose_w<<<dim3(176, 64), tb32, 0, stream>>>(Wgate, WT, 2048, 5632);
  gemm_bt<bf16, false><<<dim3(32, 44), 256, 0, stream>>>(ybf, WT, gy, nullptr, 4096, 5632, 2048);
  swiglu_k<<<45056, 256, 0, stream>>>(gy, act);
  transpose_w<<<dim3(64, 88), tb32, 0, stream>>>(Wdown, WT, 2816, 2048);
  gemm_bt<float, true><<<dim3(32, 16), 256, 0, stream>>>(act, WT, out, hbuf, 4096, 2048, 2816);
}

// Round 3
// 928.595 us; speedup vs baseline: 1.0496x; 1.0496x over previous
//
#include <hip/hip_runtime.h>
#include <hip/hip_bf16.h>
#include <cstdint>
#include <cstddef>
#include <type_traits>

// RetNet decoder layer, MI355X/gfx950.
// B=2, T=2048, D=2048, H=8, DK=DV=256, CONV_K=4, CHUNK=64, INTER=2816.
// Round 3: merged QKVG GEMM (N=8192, split epilogue), fused gated-norm in
// chunk_inner, powf->exp2f, conv/transpose launch merging. 17 launches.
// Workspace: 186.6 MB (guard at 200 MB, known-good from round 2).

typedef __hip_bfloat16 bf16;
typedef __bf16 bf16x8 __attribute__((ext_vector_type(8)));
typedef float f32x4 __attribute__((ext_vector_type(4)));

#define DEVI __device__ __forceinline__

DEVI float bf2f(bf16 x) { return __bfloat162float(x); }
DEVI bf16 f2bf(float x) { return __float2bfloat16(x); }
DEVI float siluf(float x) { return x / (1.f + __expf(-x)); }
DEVI float log2gamma(int h) {  // log2(1 - 2^-(5+h)), accurate near 1
  return log1pf(-exp2f(-5.f - (float)h)) * 1.4426950408889634f;
}

// async global->LDS, 16B per lane; LDS dest = wave-uniform base + lane*16.
#define GLL16(gp, lp)                                                  \
  __builtin_amdgcn_global_load_lds(                                    \
      (__attribute__((address_space(1))) void*)(gp),                   \
      (__attribute__((address_space(3))) void*)(lp), 16, 0, 0)

// ---------------------------------------------------------------- block reduce
DEVI float blockSum256(float v) {
  #pragma unroll
  for (int off = 32; off; off >>= 1) v += __shfl_down(v, off, 64);
  __shared__ float sm[4];
  int lane = threadIdx.x & 63, w = threadIdx.x >> 6;
  if (lane == 0) sm[w] = v;
  __syncthreads();
  return sm[0] + sm[1] + sm[2] + sm[3];
}

// ---------------------------------------------------------------- rmsnorm (D=2048) fp32 -> bf16
__global__ void rmsnorm_k(const float* __restrict__ x, const float* __restrict__ w,
                          bf16* __restrict__ out) {
  long row = blockIdx.x;
  const float* xr = x + row * 2048;
  int i0 = threadIdx.x * 4;
  float4 v0 = *(const float4*)(xr + i0);
  float4 v1 = *(const float4*)(xr + 1024 + i0);
  float ss = v0.x*v0.x + v0.y*v0.y + v0.z*v0.z + v0.w*v0.w
           + v1.x*v1.x + v1.y*v1.y + v1.z*v1.z + v1.w*v1.w;
  ss = blockSum256(ss);
  float s = rsqrtf(ss * (1.f/2048.f) + 1e-5f);
  bf16* orow = out + row * 2048;
  orow[i0+0] = f2bf(v0.x*s*w[i0+0]); orow[i0+1] = f2bf(v0.y*s*w[i0+1]);
  orow[i0+2] = f2bf(v0.z*s*w[i0+2]); orow[i0+3] = f2bf(v0.w*s*w[i0+3]);
  orow[1024+i0+0] = f2bf(v1.x*s*w[1024+i0+0]); orow[1024+i0+1] = f2bf(v1.y*s*w[1024+i0+1]);
  orow[1024+i0+2] = f2bf(v1.z*s*w[1024+i0+2]); orow[1024+i0+3] = f2bf(v1.w*s*w[1024+i0+3]);
}

// ---------------------------------------------------------------- rope table: cos/sin per (t, j<128)
__global__ void rope_init(float2* __restrict__ tab) {
  int t = blockIdx.x, j = threadIdx.x;
  double inv = exp((double)(-j) * (9.210340371976184 / 128.0));  // 10000^(-j/128)
  double ang = fmod((double)t * inv, 6.283185307179586);
  tab[t * 128 + j] = make_float2((float)cos(ang), (float)sin(ang));
}

// ---------------------------------------------------------------- weight transpose fp32(R,C) -> bf16(C,R)
__global__ void transpose_w(const float* __restrict__ in, bf16* __restrict__ out,
                            int R, int C) {
  __shared__ float tile[32][33];
  int bx = blockIdx.x * 32, by = blockIdx.y * 32;
  int tx = threadIdx.x, ty = threadIdx.y;  // 32x8
  #pragma unroll
  for (int i = 0; i < 32; i += 8)
    tile[ty + i][tx] = in[(long)(by + ty + i) * C + bx + tx];
  __syncthreads();
  #pragma unroll
  for (int i = 0; i < 32; i += 8)
    out[(long)(bx + ty + i) * R + by + tx] = f2bf(tile[tx][ty + i]);
}

// ---------------------------------------------------------------- 4x (2048,2048) weights -> one (8192,2048) B^T
__global__ void transpose_w4(const float* __restrict__ w0, const float* __restrict__ w1,
                             const float* __restrict__ w2, const float* __restrict__ w3,
                             bf16* __restrict__ out) {
  __shared__ float tile[32][33];
  const float* in = blockIdx.z == 0 ? w0 : blockIdx.z == 1 ? w1
                   : blockIdx.z == 2 ? w2 : w3;
  int bx = blockIdx.x * 32, by = blockIdx.y * 32;
  int tx = threadIdx.x, ty = threadIdx.y;
  #pragma unroll
  for (int i = 0; i < 32; i += 8)
    tile[ty + i][tx] = in[(long)(by + ty + i) * 2048 + bx + tx];
  __syncthreads();
  long rbase = (long)blockIdx.z * 2048;
  #pragma unroll
  for (int i = 0; i < 32; i += 8)
    out[(rbase + bx + ty + i) * 2048 + by + tx] = f2bf(tile[tx][ty + i]);
}

// ---------------------------------------------------------------- bf16 per-head transpose (bh,2048,256)->(bh,256,2048), optional dkc fold
__global__ void transpose_head(const bf16* __restrict__ in, bf16* __restrict__ out,
                               int withDecay) {
  __shared__ bf16 tile[32][33];
  const int bh = blockIdx.z, hh = bh & 7;
  const float lg = log2gamma(hh);
  const int t0 = blockIdx.y * 32, d0 = blockIdx.x * 32;
  const int tx = threadIdx.x, ty = threadIdx.y;
  const bf16* src = in + (long)bh * 2048 * 256;
  bf16* dst = out + (long)bh * 2048 * 256;
  #pragma unroll
  for (int i = 0; i < 32; i += 8) {
    int t = t0 + ty + i;
    float v = bf2f(src[(long)t * 256 + d0 + tx]);
    if (withDecay) v *= exp2f(lg * (float)(63 - (t & 63)));
    tile[ty + i][tx] = f2bf(v);
  }
  __syncthreads();
  #pragma unroll
  for (int i = 0; i < 32; i += 8)
    dst[(long)(d0 + ty + i) * 2048 + t0 + tx] = tile[tx][ty + i];
}

// ---------------------------------------------------------------- GEMM: C(M,N) = A(M,K)bf16 @ Bt(N,K)bf16 [+ fp32 addend]
// Split epilogue: block cols >= split write bf16 to C2 (row stride 2048).
template <typename OUT_T, bool DO_ADD>
__global__ __launch_bounds__(256) void gemm_bt(
    const bf16* __restrict__ A, const bf16* __restrict__ Bt,
    OUT_T* __restrict__ C, int ldc, bf16* __restrict__ C2, int split,
    const float* __restrict__ addend, int M, int N, int K) {
  __shared__ alignas(16) bf16 As[128 * 32];
  __shared__ alignas(16) bf16 Bs[128 * 32];
  const int tid = threadIdx.x;
  const int lane = tid & 63, wid = tid >> 6;
  const int quad = lane >> 4, l16 = lane & 15;
  const int wm = wid >> 1, wn = wid & 1;  // 2x2 waves, 64x64 each
  const long bm = (long)blockIdx.x * 128;
  const long bn = (long)blockIdx.y * 128;

  const int srow = wid * 16 + (lane >> 2);   // staging: uniform base + lane*16
  const int scol = (lane & 3) * 8;
  const bf16* pa0 = A + (bm + srow) * (long)K + scol;
  const bf16* pa1 = A + (bm + 64 + srow) * (long)K + scol;
  const bf16* pb0 = Bt + (bn + srow) * (long)K + scol;
  const bf16* pb1 = Bt + (bn + 64 + srow) * (long)K + scol;
  bf16* la0 = As + srow * 32 + scol;
  bf16* la1 = As + (64 + srow) * 32 + scol;
  bf16* lb0 = Bs + srow * 32 + scol;
  bf16* lb1 = Bs + (64 + srow) * 32 + scol;

  const f32x4 zz = {0.f, 0.f, 0.f, 0.f};
  f32x4 acc[4][4];
  #pragma unroll
  for (int i = 0; i < 4; i++)
    #pragma unroll
    for (int j = 0; j < 4; j++) acc[i][j] = zz;

  for (int k0 = 0; k0 < K; k0 += 32) {
    GLL16(pa0 + k0, la0);
    GLL16(pa1 + k0, la1);
    GLL16(pb0 + k0, lb0);
    GLL16(pb1 + k0, lb1);
    __syncthreads();
    bf16x8 a[4], b[4];
    #pragma unroll
    for (int i = 0; i < 4; i++)
      a[i] = *(const bf16x8*)(As + (wm * 64 + i * 16 + l16) * 32 + quad * 8);
    #pragma unroll
    for (int j = 0; j < 4; j++)
      b[j] = *(const bf16x8*)(Bs + (wn * 64 + j * 16 + l16) * 32 + quad * 8);
    #pragma unroll
    for (int i = 0; i < 4; i++)
      #pragma unroll
      for (int j = 0; j < 4; j++)
        acc[i][j] = __builtin_amdgcn_mfma_f32_16x16x32_bf16(a[i], b[j], acc[i][j], 0, 0, 0);
    __syncthreads();
  }

  const bool sec = (bn >= split);  // block-uniform
  #pragma unroll
  for (int i = 0; i < 4; i++)
    #pragma unroll
    for (int j = 0; j < 4; j++)
      #pragma unroll
      for (int r = 0; r < 4; r++) {
        long row = bm + wm * 64 + i * 16 + quad * 4 + r;  // C: row=quad*4+r, col=l16
        long col = bn + wn * 64 + j * 16 + l16;
        float v = acc[i][j][r];
        if (sec) {
          C2[row * 2048 + (col - split)] = f2bf(v);
        } else {
          if constexpr (DO_ADD) v += addend[row * (long)ldc + col];
          if constexpr (std::is_same<OUT_T, float>::value)
            C[row * (long)ldc + col] = v;
          else
            C[row * (long)ldc + col] = f2bf(v);
        }
      }
}

// ---------------------------------------------------------------- conv(K=4)+silu for q(rope,scaled)/k(rope)/v via blockIdx.z
__global__ void conv3(const bf16* __restrict__ u3,
                      const float* __restrict__ cwq, const float* __restrict__ cwk,
                      const float* __restrict__ cwv, const float2* __restrict__ rtab,
                      bf16* __restrict__ qb, bf16* __restrict__ kb,
                      bf16* __restrict__ vb) {
  const int bt = blockIdx.x;
  const int t = bt & 2047;
  const int b = bt >> 11;
  const int h = blockIdx.y;
  const int z = blockIdx.z;
  const long obase = ((long)(b * 8 + h) * 2048 + t) * 256;
  if (z < 2) {  // q or k: conv + silu + rope
    const float* cw = z == 0 ? cwq : cwk;
    bf16* out = z == 0 ? qb : kb;
    const float scale = z == 0 ? 0.0625f : 1.0f;  // dk^-0.5 folded into q
    const int j = threadIdx.x;  // 0..127
    const int ch1 = h * 256 + j, ch2 = ch1 + 128;
    const int c1 = z * 2048 + ch1, c2 = c1 + 128;
    float a1 = 0.f, a2 = 0.f;
    #pragma unroll
    for (int i = 0; i < 4; i++) {
      int ts = t - 3 + i;
      if (ts >= 0) {
        const bf16* up = u3 + (long)(bt - 3 + i) * 6144;
        a1 += bf2f(up[c1]) * cw[ch1 * 4 + i];
        a2 += bf2f(up[c2]) * cw[ch2 * 4 + i];
      }
    }
    a1 = siluf(a1); a2 = siluf(a2);
    float2 cssn = rtab[t * 128 + j];
    out[obase + j] = f2bf((a1 * cssn.x - a2 * cssn.y) * scale);
    out[obase + 128 + j] = f2bf((a2 * cssn.x + a1 * cssn.y) * scale);
  } else {  // v: conv + silu, 2 elems/thread
    const int j = threadIdx.x;
    #pragma unroll
    for (int half = 0; half < 2; half++) {
      const int e = j + half * 128;
      const int ch = h * 256 + e;
      const int c = 4096 + ch;
      float a = 0.f;
      #pragma unroll
      for (int i = 0; i < 4; i++) {
        int ts = t - 3 + i;
        if (ts >= 0) a += bf2f(u3[(long)(bt - 3 + i) * 6144 + c]) * cwv[ch * 4 + i];
      }
      vb[obase + e] = f2bf(siluf(a));
    }
  }
}

// ---------------------------------------------------------------- retention A: per (bh,chunk) M^T[e][d] = sum_t v[t,e]*k'[t,d]
__global__ __launch_bounds__(256) void chunk_outer(
    const bf16* __restrict__ vT, const bf16* __restrict__ kTd,
    bf16* __restrict__ states) {
  __shared__ alignas(16) bf16 lk[256 * 72];
  const int chunk = blockIdx.x, bh = blockIdx.y;
  const int tid = threadIdx.x;
  const int lane = tid & 63, wid = tid >> 6;
  const int quad = lane >> 4, l16 = lane & 15;
  const long base = (long)bh * 256 * 2048 + chunk * 64;

  #pragma unroll
  for (int it = 0; it < 8; it++) {
    int r = it * 32 + (tid >> 3);
    int cb = tid & 7;
    *(int4*)(lk + r * 72 + cb * 8) = *(const int4*)(kTd + base + (long)r * 2048 + cb * 8);
  }
  bf16x8 a[4][2];
  #pragma unroll
  for (int i = 0; i < 4; i++)
    #pragma unroll
    for (int ks = 0; ks < 2; ks++)
      a[i][ks] = *(const bf16x8*)(vT + base + (long)(wid * 64 + i * 16 + l16) * 2048 +
                                  ks * 32 + quad * 8);
  __syncthreads();

  bf16* sout = states + ((long)bh * 32 + chunk) * 65536;
  const f32x4 zz = {0.f, 0.f, 0.f, 0.f};
  for (int g = 0; g < 4; g++) {
    f32x4 acc[4][4];
    #pragma unroll
    for (int i = 0; i < 4; i++)
      #pragma unroll
      for (int j = 0; j < 4; j++) acc[i][j] = zz;
    #pragma unroll
    for (int ks = 0; ks < 2; ks++) {
      bf16x8 b[4];
      #pragma unroll
      for (int j = 0; j < 4; j++)
        b[j] = *(const bf16x8*)(lk + (g * 64 + j * 16 + l16) * 72 + ks * 32 + quad * 8);
      #pragma unroll
      for (int i = 0; i < 4; i++)
        #pragma unroll
        for (int j = 0; j < 4; j++)
          acc[i][j] = __builtin_amdgcn_mfma_f32_16x16x32_bf16(a[i][ks], b[j], acc[i][j], 0, 0, 0);
    }
    #pragma unroll
    for (int i = 0; i < 4; i++)
      #pragma unroll
      for (int j = 0; j < 4; j++)
        #pragma unroll
        for (int r = 0; r < 4; r++) {
          int e = wid * 64 + i * 16 + quad * 4 + r;
          int d = g * 64 + j * 16 + l16;
          sout[(long)e * 256 + d] = f2bf(acc[i][j][r]);
        }
  }
}

// ---------------------------------------------------------------- retention B: in-place decay scan (fp32 carry)
__global__ void state_scan(bf16* __restrict__ states) {
  const int bh = blockIdx.y, h = bh & 7;
  const float gC = exp2f(64.f * log2gamma(h));
  long idx = (long)blockIdx.x * 256 + threadIdx.x;
  bf16* p = states + (long)bh * 32 * 65536 + idx;
  float s = 0.f;
  for (int n = 0; n < 32; n++) {
    float m = bf2f(p[(long)n * 65536]);
    p[(long)n * 65536] = f2bf(s);
    s = gC * s + m;
  }
}

// ---------------------------------------------------------------- retention C: O = [A*Dm | q*di] @ [v ; S], fused gated rmsnorm
__global__ __launch_bounds__(256) void chunk_inner(
    const bf16* __restrict__ q, const bf16* __restrict__ k,
    const bf16* __restrict__ vT, const bf16* __restrict__ ST,
    const bf16* __restrict__ g, const float* __restrict__ gw,
    bf16* __restrict__ og) {
  __shared__ alignas(16) bf16 P[64 * 328];
  __shared__ float sq[64][4];
  __shared__ float sscale[64];
  const int chunk = blockIdx.x, bh = blockIdx.y;
  const int b_ = bh >> 3, h = bh & 7;
  const float lg = log2gamma(h);
  const int tid = threadIdx.x;
  const int lane = tid & 63, wid = tid >> 6;
  const int quad = lane >> 4, l16 = lane & 15;
  const long qkbase = ((long)bh * 2048 + chunk * 64) * 256;

  {  // P-right: q * di, di = gamma^(row+1)
    const int row = tid >> 2, cb = tid & 3;
    const float di = exp2f(lg * (float)(row + 1));
    const bf16* qs = q + qkbase + (long)row * 256 + cb * 64;
    bf16* pd = P + row * 328 + 64 + cb * 64;
    #pragma unroll
    for (int mb = 0; mb < 8; mb++) {
      bf16x8 v = *(const bf16x8*)(qs + mb * 8);
      #pragma unroll
      for (int e = 0; e < 8; e++) pd[mb * 8 + e] = f2bf((float)v[e] * di);
    }
  }

  {  // A = q k^T with decay mask -> P-left
    const f32x4 zz = {0.f, 0.f, 0.f, 0.f};
    f32x4 acc[4];
    #pragma unroll
    for (int j = 0; j < 4; j++) acc[j] = zz;
    #pragma unroll
    for (int ks = 0; ks < 8; ks++) {
      bf16x8 a = *(const bf16x8*)(q + qkbase + (long)(wid * 16 + l16) * 256 + ks * 32 + quad * 8);
      #pragma unroll
      for (int j = 0; j < 4; j++) {
        bf16x8 b = *(const bf16x8*)(k + qkbase + (long)(j * 16 + l16) * 256 + ks * 32 + quad * 8);
        acc[j] = __builtin_amdgcn_mfma_f32_16x16x32_bf16(a, b, acc[j], 0, 0, 0);
      }
    }
    #pragma unroll
    for (int j = 0; j < 4; j++)
      #pragma unroll
      for (int r = 0; r < 4; r++) {
        int il = wid * 16 + quad * 4 + r;
        int jl = j * 16 + l16;
        int dd = il - jl;
        float v = (dd >= 0) ? acc[j][r] * exp2f(lg * (float)dd) : 0.f;
        P[il * 328 + jl] = f2bf(v);
      }
  }
  __syncthreads();

  // O = P @ [v ; S]
  const f32x4 zz = {0.f, 0.f, 0.f, 0.f};
  f32x4 acc[4][4];
  #pragma unroll
  for (int i = 0; i < 4; i++)
    #pragma unroll
    for (int j = 0; j < 4; j++) acc[i][j] = zz;
  const long vbase = (long)bh * 256 * 2048 + chunk * 64;
  const long sbase = ((long)bh * 32 + chunk) * 65536;
  #pragma unroll
  for (int ks = 0; ks < 10; ks++) {
    bf16x8 a[4];
    #pragma unroll
    for (int i = 0; i < 4; i++)
      a[i] = *(const bf16x8*)(P + (i * 16 + l16) * 328 + ks * 32 + quad * 8);
    int kk = ks * 32 + quad * 8;
    bf16x8 b[4];
    #pragma unroll
    for (int j = 0; j < 4; j++) {
      int e = wid * 64 + j * 16 + l16;
      const bf16* src = (kk < 64) ? (vT + vbase + (long)e * 2048 + kk)
                                  : (ST + sbase + (long)e * 256 + (kk - 64));
      b[j] = *(const bf16x8*)src;
    }
    #pragma unroll
    for (int i = 0; i < 4; i++)
      #pragma unroll
      for (int j = 0; j < 4; j++)
        acc[i][j] = __builtin_amdgcn_mfma_f32_16x16x32_bf16(a[i], b[j], acc[i][j], 0, 0, 0);
  }

  // fused rmsnorm(o) * gw * silu(g):
  // per-row sum(o^2): reduce j in-lane, l16 via shfl_xor, waves via LDS.
  #pragma unroll
  for (int i = 0; i < 4; i++)
    #pragma unroll
    for (int r = 0; r < 4; r++) {
      float s = acc[i][0][r]*acc[i][0][r] + acc[i][1][r]*acc[i][1][r]
              + acc[i][2][r]*acc[i][2][r] + acc[i][3][r]*acc[i][3][r];
      s += __shfl_xor(s, 1, 64);
      s += __shfl_xor(s, 2, 64);
      s += __shfl_xor(s, 4, 64);
      s += __shfl_xor(s, 8, 64);
      if (l16 == 0) sq[i * 16 + quad * 4 + r][wid] = s;
    }
  __syncthreads();
  if (tid < 64) {
    float t = sq[tid][0] + sq[tid][1] + sq[tid][2] + sq[tid][3];
    sscale[tid] = rsqrtf(t * (1.f/256.f) + 1e-5f);
  }
  __syncthreads();

  #pragma unroll
  for (int i = 0; i < 4; i++)
    #pragma unroll
    for (int j = 0; j < 4; j++) {
      int e = wid * 64 + j * 16 + l16;
      float w = gw[e];
      #pragma unroll
      for (int r = 0; r < 4; r++) {
        int row = i * 16 + quad * 4 + r;
        long bt = (long)b_ * 2048 + chunk * 64 + row;
        float gg = bf2f(g[bt * 2048 + h * 256 + e]);
        float val = acc[i][j][r] * sscale[row] * w * siluf(gg);
        og[bt * 2048 + h * 256 + e] = f2bf(val);
      }
    }
}

// ---------------------------------------------------------------- swiglu
__global__ void swiglu_k(const bf16* __restrict__ gy, bf16* __restrict__ act) {
  long i = (long)blockIdx.x * 256 + threadIdx.x;
  long m = i / 2816, c = i - m * 2816;
  float gv = bf2f(gy[m * 5632 + c]);
  float vv = bf2f(gy[m * 5632 + 2816 + c]);
  act[i] = f2bf(siluf(gv) * vv);
}

// ================================================================ launch
extern "C" void kernel_launch(void* const* d_in, const int* in_sizes, int n_in,
                              void* d_out, int out_size, void* d_ws, size_t ws_size,
                              hipStream_t stream) {
  (void)in_sizes; (void)n_in; (void)out_size;
  const float* hidden = (const float*)d_in[0];
  const float* attn_w = (const float*)d_in[1];
  const float* Wq = (const float*)d_in[2];
  const float* Wk = (const float*)d_in[3];
  const float* Wv = (const float*)d_in[4];
  const float* Wg = (const float*)d_in[5];
  const float* Wo = (const float*)d_in[6];
  const float* cwq = (const float*)d_in[7];
  const float* cwk = (const float*)d_in[8];
  const float* cwv = (const float*)d_in[9];
  const float* gnw = (const float*)d_in[10];
  const float* mlpw = (const float*)d_in[11];
  const float* Wgate = (const float*)d_in[12];
  const float* Wdown = (const float*)d_in[13];
  float* out = (float*)d_out;
  char* ws = (char*)d_ws;

  if (ws_size < 209715200ull) return;  // guard (known-good from round 2)

  // ---- workspace layout, 186.6 MB, liveness-verified aliasing:
  // [0,33.55M)      WT region: WT4(s1-3) | kTb(s5-6)@+0, og(s8-9)@+16.78M,
  //                 WoT(s9)@+0, WgateT(s11)@+0, WdownT(s13)@+0
  // [33.55,100.66M) U region: u3(s3-4)@+0 + xbf(s2-3)@+50.33M (tile exactly);
  //                 states(s6-8)@+0; hbuf(s9-13)@+0 fp32; act(s12-13)@+33.55M
  // [100.66,167.77M) qb|kb|vTb|vnb (16.78M each);
  //                 gy(s11-12)@+0 (46.14M over qb+kb+vTb); ybf(s10-11)@+50.33M
  // [167.77,184.55M) g (s3-8)
  // [184.55,186.65M) rtab
  const size_t MB16 = 16777216ull;
  char* WTr = ws;
  bf16* WT4    = (bf16*)WTr;
  bf16* kTb    = (bf16*)WTr;
  bf16* WoT    = (bf16*)WTr;
  bf16* WgateT = (bf16*)WTr;
  bf16* WdownT = (bf16*)WTr;
  bf16* og     = (bf16*)(WTr + MB16);
  char* Ur = ws + 33554432ull;
  bf16*  u3     = (bf16*)Ur;
  bf16*  xbf    = (bf16*)(Ur + 50331648ull);
  bf16*  states = (bf16*)Ur;
  float* hbuf   = (float*)Ur;
  bf16*  act    = (bf16*)(Ur + 33554432ull);
  char* Qr = ws + 100663296ull;
  bf16* qb  = (bf16*)Qr;
  bf16* kb  = (bf16*)(Qr + MB16);
  bf16* vTb = (bf16*)(Qr + 2 * MB16);
  bf16* vnb = (bf16*)(Qr + 3 * MB16);
  bf16* gy  = (bf16*)Qr;
  bf16* ybf = (bf16*)(Qr + 50331648ull);
  bf16* g   = (bf16*)(ws + 167772160ull);
  float2* rtab = (float2*)(ws + 184549376ull);

  dim3 tb32(32, 8);

  rope_init<<<2048, 128, 0, stream>>>(rtab);
  rmsnorm_k<<<4096, 256, 0, stream>>>(hidden, attn_w, xbf);

  // merged QKVG projection: N=8192, qkv cols -> u3 (ldc 6144), g cols -> g
  transpose_w4<<<dim3(64, 64, 4), tb32, 0, stream>>>(Wq, Wk, Wv, Wg, WT4);
  gemm_bt<bf16, false><<<dim3(32, 64), 256, 0, stream>>>(
      xbf, WT4, u3, 6144, g, 6144, nullptr, 4096, 8192, 2048);

  // conv + silu (+rope) for q/k/v in one launch
  conv3<<<dim3(4096, 8, 3), 128, 0, stream>>>(u3, cwq, cwk, cwv, rtab, qb, kb, vnb);
  transpose_head<<<dim3(8, 64, 16), tb32, 0, stream>>>(kb, kTb, 1);  // fold dkc
  transpose_head<<<dim3(8, 64, 16), tb32, 0, stream>>>(vnb, vTb, 0);

  // retention (states overwrite u3+xbf — both dead here)
  chunk_outer<<<dim3(32, 16), 256, 0, stream>>>(vTb, kTb, states);
  state_scan<<<dim3(256, 16), 256, 0, stream>>>(states);
  chunk_inner<<<dim3(32, 16), 256, 0, stream>>>(qb, kb, vTb, states, g, gnw, og);

  // output projection + residual (states dead -> hbuf region free)
  transpose_w<<<dim3(64, 64), tb32, 0, stream>>>(Wo, WoT, 2048, 2048);
  gemm_bt<float, true><<<dim3(32, 16), 256, 0, stream>>>(
      og, WoT, hbuf, 2048, nullptr, 1 << 30, hidden, 4096, 2048, 2048);

  // MLP
  rmsnorm_k<<<4096, 256, 0, stream>>>(hbuf, mlpw, ybf);
  transpose_w<<<dim3(176, 64), tb32, 0, stream>>>(Wgate, WgateT, 2048, 5632);
  gemm_bt<bf16, false><<<dim3(32, 44), 256, 0, stream>>>(
      ybf, WgateT, gy, 5632, nullptr, 1 << 30, nullptr, 4096, 5632, 2048);
  swiglu_k<<<45056, 256, 0, stream>>>(gy, act);
  transpose_w<<<dim3(64, 88), tb32, 0, stream>>>(Wdown, WdownT, 2816, 2048);
  gemm_bt<float, true><<<dim3(32, 16), 256, 0, stream>>>(
      act, WdownT, out, 2048, nullptr, 1 << 30, hbuf, 4096, 2048, 2816);
}

// Round 4
// 859.145 us; speedup vs baseline: 1.1345x; 1.0808x over previous
//
#include <hip/hip_runtime.h>
#include <hip/hip_bf16.h>
#include <cstdint>
#include <cstddef>
#include <type_traits>

// RetNet decoder layer, MI355X/gfx950.
// B=2, T=2048, D=2048, H=8, DK=DV=256, CONV_K=4, CHUNK=64, INTER=2816.
// Round 4: XOR-swizzled LDS in gemm_bt (kills the 8-way ds_read_b128 bank
// conflicts while keeping the global_load_lds lane*16 staging contract),
// vectorized conv3 (bf16x4/x8) and state_scan (x8). 17 launches.
// Workspace: 186.6 MB (guard at 200 MB, known-good).

typedef __hip_bfloat16 bf16;
typedef __bf16 bf16x8 __attribute__((ext_vector_type(8)));
typedef __bf16 bf16x4 __attribute__((ext_vector_type(4)));
typedef float f32x4 __attribute__((ext_vector_type(4)));

#define DEVI __device__ __forceinline__

DEVI float bf2f(bf16 x) { return __bfloat162float(x); }
DEVI bf16 f2bf(float x) { return __float2bfloat16(x); }
DEVI float siluf(float x) { return x / (1.f + __expf(-x)); }
DEVI float log2gamma(int h) {  // log2(1 - 2^-(5+h)), accurate near 1
  return log1pf(-exp2f(-5.f - (float)h)) * 1.4426950408889634f;
}

// async global->LDS, 16B per lane; LDS dest = wave-uniform base + lane*16.
#define GLL16(gp, lp)                                                  \
  __builtin_amdgcn_global_load_lds(                                    \
      (__attribute__((address_space(1))) void*)(gp),                   \
      (__attribute__((address_space(3))) void*)(lp), 16, 0, 0)

// ---------------------------------------------------------------- block reduce
DEVI float blockSum256(float v) {
  #pragma unroll
  for (int off = 32; off; off >>= 1) v += __shfl_down(v, off, 64);
  __shared__ float sm[4];
  int lane = threadIdx.x & 63, w = threadIdx.x >> 6;
  if (lane == 0) sm[w] = v;
  __syncthreads();
  return sm[0] + sm[1] + sm[2] + sm[3];
}

// ---------------------------------------------------------------- rmsnorm (D=2048) fp32 -> bf16
__global__ void rmsnorm_k(const float* __restrict__ x, const float* __restrict__ w,
                          bf16* __restrict__ out) {
  long row = blockIdx.x;
  const float* xr = x + row * 2048;
  int i0 = threadIdx.x * 4;
  float4 v0 = *(const float4*)(xr + i0);
  float4 v1 = *(const float4*)(xr + 1024 + i0);
  float ss = v0.x*v0.x + v0.y*v0.y + v0.z*v0.z + v0.w*v0.w
           + v1.x*v1.x + v1.y*v1.y + v1.z*v1.z + v1.w*v1.w;
  ss = blockSum256(ss);
  float s = rsqrtf(ss * (1.f/2048.f) + 1e-5f);
  bf16* orow = out + row * 2048;
  orow[i0+0] = f2bf(v0.x*s*w[i0+0]); orow[i0+1] = f2bf(v0.y*s*w[i0+1]);
  orow[i0+2] = f2bf(v0.z*s*w[i0+2]); orow[i0+3] = f2bf(v0.w*s*w[i0+3]);
  orow[1024+i0+0] = f2bf(v1.x*s*w[1024+i0+0]); orow[1024+i0+1] = f2bf(v1.y*s*w[1024+i0+1]);
  orow[1024+i0+2] = f2bf(v1.z*s*w[1024+i0+2]); orow[1024+i0+3] = f2bf(v1.w*s*w[1024+i0+3]);
}

// ---------------------------------------------------------------- rope table: cos/sin per (t, j<128)
__global__ void rope_init(float2* __restrict__ tab) {
  int t = blockIdx.x, j = threadIdx.x;
  double inv = exp((double)(-j) * (9.210340371976184 / 128.0));  // 10000^(-j/128)
  double ang = fmod((double)t * inv, 6.283185307179586);
  tab[t * 128 + j] = make_float2((float)cos(ang), (float)sin(ang));
}

// ---------------------------------------------------------------- weight transpose fp32(R,C) -> bf16(C,R)
__global__ void transpose_w(const float* __restrict__ in, bf16* __restrict__ out,
                            int R, int C) {
  __shared__ float tile[32][33];
  int bx = blockIdx.x * 32, by = blockIdx.y * 32;
  int tx = threadIdx.x, ty = threadIdx.y;  // 32x8
  #pragma unroll
  for (int i = 0; i < 32; i += 8)
    tile[ty + i][tx] = in[(long)(by + ty + i) * C + bx + tx];
  __syncthreads();
  #pragma unroll
  for (int i = 0; i < 32; i += 8)
    out[(long)(bx + ty + i) * R + by + tx] = f2bf(tile[tx][ty + i]);
}

// ---------------------------------------------------------------- 4x (2048,2048) weights -> one (8192,2048) B^T
__global__ void transpose_w4(const float* __restrict__ w0, const float* __restrict__ w1,
                             const float* __restrict__ w2, const float* __restrict__ w3,
                             bf16* __restrict__ out) {
  __shared__ float tile[32][33];
  const float* in = blockIdx.z == 0 ? w0 : blockIdx.z == 1 ? w1
                   : blockIdx.z == 2 ? w2 : w3;
  int bx = blockIdx.x * 32, by = blockIdx.y * 32;
  int tx = threadIdx.x, ty = threadIdx.y;
  #pragma unroll
  for (int i = 0; i < 32; i += 8)
    tile[ty + i][tx] = in[(long)(by + ty + i) * 2048 + bx + tx];
  __syncthreads();
  long rbase = (long)blockIdx.z * 2048;
  #pragma unroll
  for (int i = 0; i < 32; i += 8)
    out[(rbase + bx + ty + i) * 2048 + by + tx] = f2bf(tile[tx][ty + i]);
}

// ---------------------------------------------------------------- bf16 per-head transpose (bh,2048,256)->(bh,256,2048), optional dkc fold
__global__ void transpose_head(const bf16* __restrict__ in, bf16* __restrict__ out,
                               int withDecay) {
  __shared__ bf16 tile[32][33];
  const int bh = blockIdx.z, hh = bh & 7;
  const float lg = log2gamma(hh);
  const int t0 = blockIdx.y * 32, d0 = blockIdx.x * 32;
  const int tx = threadIdx.x, ty = threadIdx.y;
  const bf16* src = in + (long)bh * 2048 * 256;
  bf16* dst = out + (long)bh * 2048 * 256;
  #pragma unroll
  for (int i = 0; i < 32; i += 8) {
    int t = t0 + ty + i;
    float v = bf2f(src[(long)t * 256 + d0 + tx]);
    if (withDecay) v *= exp2f(lg * (float)(63 - (t & 63)));
    tile[ty + i][tx] = f2bf(v);
  }
  __syncthreads();
  #pragma unroll
  for (int i = 0; i < 32; i += 8)
    dst[(long)(d0 + ty + i) * 2048 + t0 + tx] = tile[tx][ty + i];
}

// ---------------------------------------------------------------- GEMM: C(M,N) = A(M,K)bf16 @ Bt(N,K)bf16 [+ fp32 addend]
// XOR-swizzled LDS: physical slot (row, cs) holds global col-block
// cs ^ ((row>>1)&3); fragment reads use quad ^ ((l16>>1)&3) -> 2 lanes per
// bank-quad (free per m136) instead of 8-way. Staging keeps the lane*16
// contract; lanes of a row permute within the same 64-B global segment.
template <typename OUT_T, bool DO_ADD>
__global__ __launch_bounds__(256) void gemm_bt(
    const bf16* __restrict__ A, const bf16* __restrict__ Bt,
    OUT_T* __restrict__ C, int ldc, bf16* __restrict__ C2, int split,
    const float* __restrict__ addend, int M, int N, int K) {
  __shared__ alignas(16) bf16 As[128 * 32];
  __shared__ alignas(16) bf16 Bs[128 * 32];
  const int tid = threadIdx.x;
  const int lane = tid & 63, wid = tid >> 6;
  const int quad = lane >> 4, l16 = lane & 15;
  const int wm = wid >> 1, wn = wid & 1;  // 2x2 waves, 64x64 each
  const long bm = (long)blockIdx.x * 128;
  const long bn = (long)blockIdx.y * 128;

  const int srow = wid * 16 + (lane >> 2);                   // staged row
  const int scolP = (lane & 3) * 8;                          // physical LDS col
  const int scolG = (((lane & 3) ^ ((srow >> 1) & 3))) * 8;  // swizzled global col
  const bf16* pa0 = A + (bm + srow) * (long)K + scolG;
  const bf16* pa1 = A + (bm + 64 + srow) * (long)K + scolG;
  const bf16* pb0 = Bt + (bn + srow) * (long)K + scolG;
  const bf16* pb1 = Bt + (bn + 64 + srow) * (long)K + scolG;
  bf16* la0 = As + srow * 32 + scolP;
  bf16* la1 = As + (64 + srow) * 32 + scolP;
  bf16* lb0 = Bs + srow * 32 + scolP;
  bf16* lb1 = Bs + (64 + srow) * 32 + scolP;

  const int fcol = ((quad ^ ((l16 >> 1) & 3)) * 8);  // fragment-read swizzle

  const f32x4 zz = {0.f, 0.f, 0.f, 0.f};
  f32x4 acc[4][4];
  #pragma unroll
  for (int i = 0; i < 4; i++)
    #pragma unroll
    for (int j = 0; j < 4; j++) acc[i][j] = zz;

  for (int k0 = 0; k0 < K; k0 += 32) {
    GLL16(pa0 + k0, la0);
    GLL16(pa1 + k0, la1);
    GLL16(pb0 + k0, lb0);
    GLL16(pb1 + k0, lb1);
    __syncthreads();
    bf16x8 a[4], b[4];
    #pragma unroll
    for (int i = 0; i < 4; i++)
      a[i] = *(const bf16x8*)(As + (wm * 64 + i * 16 + l16) * 32 + fcol);
    #pragma unroll
    for (int j = 0; j < 4; j++)
      b[j] = *(const bf16x8*)(Bs + (wn * 64 + j * 16 + l16) * 32 + fcol);
    #pragma unroll
    for (int i = 0; i < 4; i++)
      #pragma unroll
      for (int j = 0; j < 4; j++)
        acc[i][j] = __builtin_amdgcn_mfma_f32_16x16x32_bf16(a[i], b[j], acc[i][j], 0, 0, 0);
    __syncthreads();
  }

  const bool sec = (bn >= split);  // block-uniform
  #pragma unroll
  for (int i = 0; i < 4; i++)
    #pragma unroll
    for (int j = 0; j < 4; j++)
      #pragma unroll
      for (int r = 0; r < 4; r++) {
        long row = bm + wm * 64 + i * 16 + quad * 4 + r;  // C: row=quad*4+r, col=l16
        long col = bn + wn * 64 + j * 16 + l16;
        float v = acc[i][j][r];
        if (sec) {
          C2[row * 2048 + (col - split)] = f2bf(v);
        } else {
          if constexpr (DO_ADD) v += addend[row * (long)ldc + col];
          if constexpr (std::is_same<OUT_T, float>::value)
            C[row * (long)ldc + col] = v;
          else
            C[row * (long)ldc + col] = f2bf(v);
        }
      }
}

// ---------------------------------------------------------------- conv(K=4)+silu, vectorized; z=0 q(rope,scale) z=1 k(rope) z=2 v
__global__ void conv3(const bf16* __restrict__ u3,
                      const float* __restrict__ cwq, const float* __restrict__ cwk,
                      const float* __restrict__ cwv, const float2* __restrict__ rtab,
                      bf16* __restrict__ qb, bf16* __restrict__ kb,
                      bf16* __restrict__ vb) {
  const int bt = blockIdx.x;
  const int t = bt & 2047;
  const int b = bt >> 11;
  const int z = blockIdx.y;
  const int tid = threadIdx.x;  // 256
  const int h = tid >> 5;
  if (z < 2) {  // q/k: conv + silu + rope, 4 (j, j+128) pairs per thread
    const float* cw = z == 0 ? cwq : cwk;
    bf16* out = z == 0 ? qb : kb;
    const float scale = z == 0 ? 0.0625f : 1.0f;  // dk^-0.5 folded into q
    const int j0 = (tid & 31) * 4;
    const int ch1 = h * 256 + j0, ch2 = ch1 + 128;
    const int c1 = z * 2048 + ch1, c2 = c1 + 128;
    f32x4 w1[4], w2[4];
    #pragma unroll
    for (int e = 0; e < 4; e++) {
      w1[e] = *(const f32x4*)(cw + (ch1 + e) * 4);
      w2[e] = *(const f32x4*)(cw + (ch2 + e) * 4);
    }
    float a1[4] = {0.f, 0.f, 0.f, 0.f}, a2[4] = {0.f, 0.f, 0.f, 0.f};
    #pragma unroll
    for (int i = 0; i < 4; i++) {
      int ts = t - 3 + i;
      if (ts >= 0) {
        const bf16* up = u3 + (long)(bt - 3 + i) * 6144;
        bf16x4 v1 = *(const bf16x4*)(up + c1);
        bf16x4 v2 = *(const bf16x4*)(up + c2);
        #pragma unroll
        for (int e = 0; e < 4; e++) {
          a1[e] += (float)v1[e] * w1[e][i];
          a2[e] += (float)v2[e] * w2[e][i];
        }
      }
    }
    f32x4 r01 = *(const f32x4*)(rtab + t * 128 + j0);      // c0,s0,c1,s1
    f32x4 r23 = *(const f32x4*)(rtab + t * 128 + j0 + 2);  // c2,s2,c3,s3
    float cs[4] = {r01[0], r01[2], r23[0], r23[2]};
    float sn[4] = {r01[1], r01[3], r23[1], r23[3]};
    bf16x4 o1, o2;
    #pragma unroll
    for (int e = 0; e < 4; e++) {
      float s1 = siluf(a1[e]), s2 = siluf(a2[e]);
      o1[e] = (__bf16)((s1 * cs[e] - s2 * sn[e]) * scale);
      o2[e] = (__bf16)((s2 * cs[e] + s1 * sn[e]) * scale);
    }
    long obase = ((long)(b * 8 + h) * 2048 + t) * 256;
    *(bf16x4*)(out + obase + j0) = o1;
    *(bf16x4*)(out + obase + 128 + j0) = o2;
  } else {  // v: conv + silu, 8 contiguous per thread
    const int e0 = (tid & 31) * 8;
    const int ch = h * 256 + e0;
    const int c = 4096 + ch;
    f32x4 w[8];
    #pragma unroll
    for (int e = 0; e < 8; e++) w[e] = *(const f32x4*)(cwv + (ch + e) * 4);
    float a[8] = {0.f, 0.f, 0.f, 0.f, 0.f, 0.f, 0.f, 0.f};
    #pragma unroll
    for (int i = 0; i < 4; i++) {
      int ts = t - 3 + i;
      if (ts >= 0) {
        bf16x8 v = *(const bf16x8*)(u3 + (long)(bt - 3 + i) * 6144 + c);
        #pragma unroll
        for (int e = 0; e < 8; e++) a[e] += (float)v[e] * w[e][i];
      }
    }
    bf16x8 o;
    #pragma unroll
    for (int e = 0; e < 8; e++) o[e] = (__bf16)siluf(a[e]);
    *(bf16x8*)(vb + ((long)(b * 8 + h) * 2048 + t) * 256 + e0) = o;
  }
}

// ---------------------------------------------------------------- retention A: per (bh,chunk) M^T[e][d] = sum_t v[t,e]*k'[t,d]
__global__ __launch_bounds__(256) void chunk_outer(
    const bf16* __restrict__ vT, const bf16* __restrict__ kTd,
    bf16* __restrict__ states) {
  __shared__ alignas(16) bf16 lk[256 * 72];
  const int chunk = blockIdx.x, bh = blockIdx.y;
  const int tid = threadIdx.x;
  const int lane = tid & 63, wid = tid >> 6;
  const int quad = lane >> 4, l16 = lane & 15;
  const long base = (long)bh * 256 * 2048 + chunk * 64;

  #pragma unroll
  for (int it = 0; it < 8; it++) {
    int r = it * 32 + (tid >> 3);
    int cb = tid & 7;
    *(int4*)(lk + r * 72 + cb * 8) = *(const int4*)(kTd + base + (long)r * 2048 + cb * 8);
  }
  bf16x8 a[4][2];
  #pragma unroll
  for (int i = 0; i < 4; i++)
    #pragma unroll
    for (int ks = 0; ks < 2; ks++)
      a[i][ks] = *(const bf16x8*)(vT + base + (long)(wid * 64 + i * 16 + l16) * 2048 +
                                  ks * 32 + quad * 8);
  __syncthreads();

  bf16* sout = states + ((long)bh * 32 + chunk) * 65536;
  const f32x4 zz = {0.f, 0.f, 0.f, 0.f};
  for (int g = 0; g < 4; g++) {
    f32x4 acc[4][4];
    #pragma unroll
    for (int i = 0; i < 4; i++)
      #pragma unroll
      for (int j = 0; j < 4; j++) acc[i][j] = zz;
    #pragma unroll
    for (int ks = 0; ks < 2; ks++) {
      bf16x8 b[4];
      #pragma unroll
      for (int j = 0; j < 4; j++)
        b[j] = *(const bf16x8*)(lk + (g * 64 + j * 16 + l16) * 72 + ks * 32 + quad * 8);
      #pragma unroll
      for (int i = 0; i < 4; i++)
        #pragma unroll
        for (int j = 0; j < 4; j++)
          acc[i][j] = __builtin_amdgcn_mfma_f32_16x16x32_bf16(a[i][ks], b[j], acc[i][j], 0, 0, 0);
    }
    #pragma unroll
    for (int i = 0; i < 4; i++)
      #pragma unroll
      for (int j = 0; j < 4; j++)
        #pragma unroll
        for (int r = 0; r < 4; r++) {
          int e = wid * 64 + i * 16 + quad * 4 + r;
          int d = g * 64 + j * 16 + l16;
          sout[(long)e * 256 + d] = f2bf(acc[i][j][r]);
        }
  }
}

// ---------------------------------------------------------------- retention B: in-place decay scan, 8 elems/thread (vectorized)
__global__ void state_scan(bf16* __restrict__ states) {
  const int bh = blockIdx.y, h = bh & 7;
  const float gC = exp2f(64.f * log2gamma(h));
  long idx = ((long)blockIdx.x * 256 + threadIdx.x) * 8;  // grid.x=32 -> 65536
  bf16* p = states + (long)bh * 32 * 65536 + idx;
  float s[8] = {0.f, 0.f, 0.f, 0.f, 0.f, 0.f, 0.f, 0.f};
  for (int n = 0; n < 32; n++) {
    bf16x8 m = *(const bf16x8*)(p + (long)n * 65536);
    bf16x8 o;
    #pragma unroll
    for (int e = 0; e < 8; e++) {
      o[e] = (__bf16)s[e];
      s[e] = gC * s[e] + (float)m[e];
    }
    *(bf16x8*)(p + (long)n * 65536) = o;
  }
}

// ---------------------------------------------------------------- retention C: O = [A*Dm | q*di] @ [v ; S], fused gated rmsnorm
__global__ __launch_bounds__(256) void chunk_inner(
    const bf16* __restrict__ q, const bf16* __restrict__ k,
    const bf16* __restrict__ vT, const bf16* __restrict__ ST,
    const bf16* __restrict__ g, const float* __restrict__ gw,
    bf16* __restrict__ og) {
  __shared__ alignas(16) bf16 P[64 * 328];
  __shared__ float sq[64][4];
  __shared__ float sscale[64];
  const int chunk = blockIdx.x, bh = blockIdx.y;
  const int b_ = bh >> 3, h = bh & 7;
  const float lg = log2gamma(h);
  const int tid = threadIdx.x;
  const int lane = tid & 63, wid = tid >> 6;
  const int quad = lane >> 4, l16 = lane & 15;
  const long qkbase = ((long)bh * 2048 + chunk * 64) * 256;

  {  // P-right: q * di, di = gamma^(row+1)
    const int row = tid >> 2, cb = tid & 3;
    const float di = exp2f(lg * (float)(row + 1));
    const bf16* qs = q + qkbase + (long)row * 256 + cb * 64;
    bf16* pd = P + row * 328 + 64 + cb * 64;
    #pragma unroll
    for (int mb = 0; mb < 8; mb++) {
      bf16x8 v = *(const bf16x8*)(qs + mb * 8);
      #pragma unroll
      for (int e = 0; e < 8; e++) pd[mb * 8 + e] = f2bf((float)v[e] * di);
    }
  }

  {  // A = q k^T with decay mask -> P-left
    const f32x4 zz = {0.f, 0.f, 0.f, 0.f};
    f32x4 acc[4];
    #pragma unroll
    for (int j = 0; j < 4; j++) acc[j] = zz;
    #pragma unroll
    for (int ks = 0; ks < 8; ks++) {
      bf16x8 a = *(const bf16x8*)(q + qkbase + (long)(wid * 16 + l16) * 256 + ks * 32 + quad * 8);
      #pragma unroll
      for (int j = 0; j < 4; j++) {
        bf16x8 b = *(const bf16x8*)(k + qkbase + (long)(j * 16 + l16) * 256 + ks * 32 + quad * 8);
        acc[j] = __builtin_amdgcn_mfma_f32_16x16x32_bf16(a, b, acc[j], 0, 0, 0);
      }
    }
    #pragma unroll
    for (int j = 0; j < 4; j++)
      #pragma unroll
      for (int r = 0; r < 4; r++) {
        int il = wid * 16 + quad * 4 + r;
        int jl = j * 16 + l16;
        int dd = il - jl;
        float v = (dd >= 0) ? acc[j][r] * exp2f(lg * (float)dd) : 0.f;
        P[il * 328 + jl] = f2bf(v);
      }
  }
  __syncthreads();

  // O = P @ [v ; S]
  const f32x4 zz = {0.f, 0.f, 0.f, 0.f};
  f32x4 acc[4][4];
  #pragma unroll
  for (int i = 0; i < 4; i++)
    #pragma unroll
    for (int j = 0; j < 4; j++) acc[i][j] = zz;
  const long vbase = (long)bh * 256 * 2048 + chunk * 64;
  const long sbase = ((long)bh * 32 + chunk) * 65536;
  #pragma unroll
  for (int ks = 0; ks < 10; ks++) {
    bf16x8 a[4];
    #pragma unroll
    for (int i = 0; i < 4; i++)
      a[i] = *(const bf16x8*)(P + (i * 16 + l16) * 328 + ks * 32 + quad * 8);
    int kk = ks * 32 + quad * 8;
    bf16x8 b[4];
    #pragma unroll
    for (int j = 0; j < 4; j++) {
      int e = wid * 64 + j * 16 + l16;
      const bf16* src = (kk < 64) ? (vT + vbase + (long)e * 2048 + kk)
                                  : (ST + sbase + (long)e * 256 + (kk - 64));
      b[j] = *(const bf16x8*)src;
    }
    #pragma unroll
    for (int i = 0; i < 4; i++)
      #pragma unroll
      for (int j = 0; j < 4; j++)
        acc[i][j] = __builtin_amdgcn_mfma_f32_16x16x32_bf16(a[i], b[j], acc[i][j], 0, 0, 0);
  }

  // fused rmsnorm(o) * gw * silu(g)
  #pragma unroll
  for (int i = 0; i < 4; i++)
    #pragma unroll
    for (int r = 0; r < 4; r++) {
      float s = acc[i][0][r]*acc[i][0][r] + acc[i][1][r]*acc[i][1][r]
              + acc[i][2][r]*acc[i][2][r] + acc[i][3][r]*acc[i][3][r];
      s += __shfl_xor(s, 1, 64);
      s += __shfl_xor(s, 2, 64);
      s += __shfl_xor(s, 4, 64);
      s += __shfl_xor(s, 8, 64);
      if (l16 == 0) sq[i * 16 + quad * 4 + r][wid] = s;
    }
  __syncthreads();
  if (tid < 64) {
    float t = sq[tid][0] + sq[tid][1] + sq[tid][2] + sq[tid][3];
    sscale[tid] = rsqrtf(t * (1.f/256.f) + 1e-5f);
  }
  __syncthreads();

  #pragma unroll
  for (int i = 0; i < 4; i++)
    #pragma unroll
    for (int j = 0; j < 4; j++) {
      int e = wid * 64 + j * 16 + l16;
      float w = gw[e];
      #pragma unroll
      for (int r = 0; r < 4; r++) {
        int row = i * 16 + quad * 4 + r;
        long bt = (long)b_ * 2048 + chunk * 64 + row;
        float gg = bf2f(g[bt * 2048 + h * 256 + e]);
        float val = acc[i][j][r] * sscale[row] * w * siluf(gg);
        og[bt * 2048 + h * 256 + e] = f2bf(val);
      }
    }
}

// ---------------------------------------------------------------- swiglu
__global__ void swiglu_k(const bf16* __restrict__ gy, bf16* __restrict__ act) {
  long i = (long)blockIdx.x * 256 + threadIdx.x;
  long m = i / 2816, c = i - m * 2816;
  float gv = bf2f(gy[m * 5632 + c]);
  float vv = bf2f(gy[m * 5632 + 2816 + c]);
  act[i] = f2bf(siluf(gv) * vv);
}

// ================================================================ launch
extern "C" void kernel_launch(void* const* d_in, const int* in_sizes, int n_in,
                              void* d_out, int out_size, void* d_ws, size_t ws_size,
                              hipStream_t stream) {
  (void)in_sizes; (void)n_in; (void)out_size;
  const float* hidden = (const float*)d_in[0];
  const float* attn_w = (const float*)d_in[1];
  const float* Wq = (const float*)d_in[2];
  const float* Wk = (const float*)d_in[3];
  const float* Wv = (const float*)d_in[4];
  const float* Wg = (const float*)d_in[5];
  const float* Wo = (const float*)d_in[6];
  const float* cwq = (const float*)d_in[7];
  const float* cwk = (const float*)d_in[8];
  const float* cwv = (const float*)d_in[9];
  const float* gnw = (const float*)d_in[10];
  const float* mlpw = (const float*)d_in[11];
  const float* Wgate = (const float*)d_in[12];
  const float* Wdown = (const float*)d_in[13];
  float* out = (float*)d_out;
  char* ws = (char*)d_ws;

  if (ws_size < 209715200ull) return;  // guard (known-good)

  // ---- workspace layout, 186.6 MB, liveness-verified aliasing (round 3)
  const size_t MB16 = 16777216ull;
  char* WTr = ws;
  bf16* WT4    = (bf16*)WTr;
  bf16* kTb    = (bf16*)WTr;
  bf16* WoT    = (bf16*)WTr;
  bf16* WgateT = (bf16*)WTr;
  bf16* WdownT = (bf16*)WTr;
  bf16* og     = (bf16*)(WTr + MB16);
  char* Ur = ws + 33554432ull;
  bf16*  u3     = (bf16*)Ur;
  bf16*  xbf    = (bf16*)(Ur + 50331648ull);
  bf16*  states = (bf16*)Ur;
  float* hbuf   = (float*)Ur;
  bf16*  act    = (bf16*)(Ur + 33554432ull);
  char* Qr = ws + 100663296ull;
  bf16* qb  = (bf16*)Qr;
  bf16* kb  = (bf16*)(Qr + MB16);
  bf16* vTb = (bf16*)(Qr + 2 * MB16);
  bf16* vnb = (bf16*)(Qr + 3 * MB16);
  bf16* gy  = (bf16*)Qr;
  bf16* ybf = (bf16*)(Qr + 50331648ull);
  bf16* g   = (bf16*)(ws + 167772160ull);
  float2* rtab = (float2*)(ws + 184549376ull);

  dim3 tb32(32, 8);

  rope_init<<<2048, 128, 0, stream>>>(rtab);
  rmsnorm_k<<<4096, 256, 0, stream>>>(hidden, attn_w, xbf);

  // merged QKVG projection: N=8192, qkv cols -> u3 (ldc 6144), g cols -> g
  transpose_w4<<<dim3(64, 64, 4), tb32, 0, stream>>>(Wq, Wk, Wv, Wg, WT4);
  gemm_bt<bf16, false><<<dim3(32, 64), 256, 0, stream>>>(
      xbf, WT4, u3, 6144, g, 6144, nullptr, 4096, 8192, 2048);

  // conv + silu (+rope) for q/k/v in one launch (vectorized)
  conv3<<<dim3(4096, 3), 256, 0, stream>>>(u3, cwq, cwk, cwv, rtab, qb, kb, vnb);
  transpose_head<<<dim3(8, 64, 16), tb32, 0, stream>>>(kb, kTb, 1);  // fold dkc
  transpose_head<<<dim3(8, 64, 16), tb32, 0, stream>>>(vnb, vTb, 0);

  // retention (states overwrite u3+xbf — both dead here)
  chunk_outer<<<dim3(32, 16), 256, 0, stream>>>(vTb, kTb, states);
  state_scan<<<dim3(32, 16), 256, 0, stream>>>(states);
  chunk_inner<<<dim3(32, 16), 256, 0, stream>>>(qb, kb, vTb, states, g, gnw, og);

  // output projection + residual (states dead -> hbuf region free)
  transpose_w<<<dim3(64, 64), tb32, 0, stream>>>(Wo, WoT, 2048, 2048);
  gemm_bt<float, true><<<dim3(32, 16), 256, 0, stream>>>(
      og, WoT, hbuf, 2048, nullptr, 1 << 30, hidden, 4096, 2048, 2048);

  // MLP
  rmsnorm_k<<<4096, 256, 0, stream>>>(hbuf, mlpw, ybf);
  transpose_w<<<dim3(176, 64), tb32, 0, stream>>>(Wgate, WgateT, 2048, 5632);
  gemm_bt<bf16, false><<<dim3(32, 44), 256, 0, stream>>>(
      ybf, WgateT, gy, 5632, nullptr, 1 << 30, nullptr, 4096, 5632, 2048);
  swiglu_k<<<45056, 256, 0, stream>>>(gy, act);
  transpose_w<<<dim3(64, 88), tb32, 0, stream>>>(Wdown, WdownT, 2816, 2048);
  gemm_bt<float, true><<<dim3(32, 16), 256, 0, stream>>>(
      act, WdownT, out, 2048, nullptr, 1 << 30, hbuf, 4096, 2048, 2816);
}

// Round 5
// 795.142 us; speedup vs baseline: 1.2258x; 1.0805x over previous
//
#include <hip/hip_runtime.h>
#include <hip/hip_bf16.h>
#include <cstdint>
#include <cstddef>
#include <type_traits>

// RetNet decoder layer, MI355X/gfx950.
// B=2, T=2048, D=2048, H=8, DK=DV=256, CONV_K=4, CHUNK=64, INTER=2816.
// Round 5: BK=64 GEMM K-loop (half the barrier drains; 32 KB LDS keeps
// 5 blocks/CU), swiglu fused into the W_gate GEMM epilogue via permuted
// WgateT (gate/value column interleave at 16-col granularity). 16 launches.
// Workspace: 186.6 MB (guard at 200 MB, known-good).

typedef __hip_bfloat16 bf16;
typedef __bf16 bf16x8 __attribute__((ext_vector_type(8)));
typedef __bf16 bf16x4 __attribute__((ext_vector_type(4)));
typedef float f32x4 __attribute__((ext_vector_type(4)));

#define DEVI __device__ __forceinline__

DEVI float bf2f(bf16 x) { return __bfloat162float(x); }
DEVI bf16 f2bf(float x) { return __float2bfloat16(x); }
DEVI float siluf(float x) { return x / (1.f + __expf(-x)); }
DEVI float log2gamma(int h) {  // log2(1 - 2^-(5+h)), accurate near 1
  return log1pf(-exp2f(-5.f - (float)h)) * 1.4426950408889634f;
}

// async global->LDS, 16B per lane; LDS dest = wave-uniform base + lane*16.
#define GLL16(gp, lp)                                                  \
  __builtin_amdgcn_global_load_lds(                                    \
      (__attribute__((address_space(1))) void*)(gp),                   \
      (__attribute__((address_space(3))) void*)(lp), 16, 0, 0)

// ---------------------------------------------------------------- block reduce
DEVI float blockSum256(float v) {
  #pragma unroll
  for (int off = 32; off; off >>= 1) v += __shfl_down(v, off, 64);
  __shared__ float sm[4];
  int lane = threadIdx.x & 63, w = threadIdx.x >> 6;
  if (lane == 0) sm[w] = v;
  __syncthreads();
  return sm[0] + sm[1] + sm[2] + sm[3];
}

// ---------------------------------------------------------------- rmsnorm (D=2048) fp32 -> bf16
__global__ void rmsnorm_k(const float* __restrict__ x, const float* __restrict__ w,
                          bf16* __restrict__ out) {
  long row = blockIdx.x;
  const float* xr = x + row * 2048;
  int i0 = threadIdx.x * 4;
  float4 v0 = *(const float4*)(xr + i0);
  float4 v1 = *(const float4*)(xr + 1024 + i0);
  float ss = v0.x*v0.x + v0.y*v0.y + v0.z*v0.z + v0.w*v0.w
           + v1.x*v1.x + v1.y*v1.y + v1.z*v1.z + v1.w*v1.w;
  ss = blockSum256(ss);
  float s = rsqrtf(ss * (1.f/2048.f) + 1e-5f);
  bf16* orow = out + row * 2048;
  orow[i0+0] = f2bf(v0.x*s*w[i0+0]); orow[i0+1] = f2bf(v0.y*s*w[i0+1]);
  orow[i0+2] = f2bf(v0.z*s*w[i0+2]); orow[i0+3] = f2bf(v0.w*s*w[i0+3]);
  orow[1024+i0+0] = f2bf(v1.x*s*w[1024+i0+0]); orow[1024+i0+1] = f2bf(v1.y*s*w[1024+i0+1]);
  orow[1024+i0+2] = f2bf(v1.z*s*w[1024+i0+2]); orow[1024+i0+3] = f2bf(v1.w*s*w[1024+i0+3]);
}

// ---------------------------------------------------------------- rope table: cos/sin per (t, j<128)
__global__ void rope_init(float2* __restrict__ tab) {
  int t = blockIdx.x, j = threadIdx.x;
  double inv = exp((double)(-j) * (9.210340371976184 / 128.0));  // 10000^(-j/128)
  double ang = fmod((double)t * inv, 6.283185307179586);
  tab[t * 128 + j] = make_float2((float)cos(ang), (float)sin(ang));
}

// ---------------------------------------------------------------- weight transpose fp32(R,C) -> bf16(C,R)
__global__ void transpose_w(const float* __restrict__ in, bf16* __restrict__ out,
                            int R, int C) {
  __shared__ float tile[32][33];
  int bx = blockIdx.x * 32, by = blockIdx.y * 32;
  int tx = threadIdx.x, ty = threadIdx.y;  // 32x8
  #pragma unroll
  for (int i = 0; i < 32; i += 8)
    tile[ty + i][tx] = in[(long)(by + ty + i) * C + bx + tx];
  __syncthreads();
  #pragma unroll
  for (int i = 0; i < 32; i += 8)
    out[(long)(bx + ty + i) * R + by + tx] = f2bf(tile[tx][ty + i]);
}

// ---------------------------------------------------------------- 4x (2048,2048) weights -> one (8192,2048) B^T
__global__ void transpose_w4(const float* __restrict__ w0, const float* __restrict__ w1,
                             const float* __restrict__ w2, const float* __restrict__ w3,
                             bf16* __restrict__ out) {
  __shared__ float tile[32][33];
  const float* in = blockIdx.z == 0 ? w0 : blockIdx.z == 1 ? w1
                   : blockIdx.z == 2 ? w2 : w3;
  int bx = blockIdx.x * 32, by = blockIdx.y * 32;
  int tx = threadIdx.x, ty = threadIdx.y;
  #pragma unroll
  for (int i = 0; i < 32; i += 8)
    tile[ty + i][tx] = in[(long)(by + ty + i) * 2048 + bx + tx];
  __syncthreads();
  long rbase = (long)blockIdx.z * 2048;
  #pragma unroll
  for (int i = 0; i < 32; i += 8)
    out[(rbase + bx + ty + i) * 2048 + by + tx] = f2bf(tile[tx][ty + i]);
}

// ---------------------------------------------------------------- Wgate (2048,5632) -> permuted WgateT (5632,2048) bf16
// out row r: group g=r>>4; source col = (g&1)*2816 + (g>>1)*16 + (r&15).
// Interleaves gate/value columns in 16-wide groups so the GEMM epilogue has
// gate (j even) and value (j odd) for the SAME act column in one lane.
__global__ void transpose_wgate(const float* __restrict__ in, bf16* __restrict__ out) {
  __shared__ float tile[32][33];
  int bx = blockIdx.x * 32, by = blockIdx.y * 32;  // bx: out row r, by: k
  int tx = threadIdx.x, ty = threadIdx.y;
  int r = bx + tx;
  int gidx = r >> 4;
  int scol = ((gidx & 1) ? 2816 : 0) + ((gidx >> 1) << 4) + (r & 15);
  #pragma unroll
  for (int i = 0; i < 32; i += 8)
    tile[ty + i][tx] = in[(long)(by + ty + i) * 5632 + scol];
  __syncthreads();
  #pragma unroll
  for (int i = 0; i < 32; i += 8)
    out[(long)(bx + ty + i) * 2048 + by + tx] = f2bf(tile[tx][ty + i]);
}

// ---------------------------------------------------------------- bf16 per-head transpose (bh,2048,256)->(bh,256,2048), optional dkc fold
__global__ void transpose_head(const bf16* __restrict__ in, bf16* __restrict__ out,
                               int withDecay) {
  __shared__ bf16 tile[32][33];
  const int bh = blockIdx.z, hh = bh & 7;
  const float lg = log2gamma(hh);
  const int t0 = blockIdx.y * 32, d0 = blockIdx.x * 32;
  const int tx = threadIdx.x, ty = threadIdx.y;
  const bf16* src = in + (long)bh * 2048 * 256;
  bf16* dst = out + (long)bh * 2048 * 256;
  #pragma unroll
  for (int i = 0; i < 32; i += 8) {
    int t = t0 + ty + i;
    float v = bf2f(src[(long)t * 256 + d0 + tx]);
    if (withDecay) v *= exp2f(lg * (float)(63 - (t & 63)));
    tile[ty + i][tx] = f2bf(v);
  }
  __syncthreads();
  #pragma unroll
  for (int i = 0; i < 32; i += 8)
    dst[(long)(d0 + ty + i) * 2048 + t0 + tx] = tile[tx][ty + i];
}

// ---------------------------------------------------------------- GEMM: C(M,N) = A(M,K)bf16 @ Bt(N,K)bf16, BK=64
// XOR-swizzled LDS (conflict-free, verified round 4); BK=64 halves the
// per-block __syncthreads count vs BK=32. Epilogue variants: fp32/bf16 out,
// +fp32 addend, col-split to bf16 C2, or fused swiglu (permuted-B layout).
template <typename OUT_T, bool DO_ADD, bool DO_SWIGLU>
__global__ __launch_bounds__(256) void gemm_bt(
    const bf16* __restrict__ A, const bf16* __restrict__ Bt,
    OUT_T* __restrict__ C, int ldc, bf16* __restrict__ C2, int split,
    const float* __restrict__ addend, int M, int N, int K) {
  __shared__ alignas(16) bf16 As[128 * 64];
  __shared__ alignas(16) bf16 Bs[128 * 64];
  const int tid = threadIdx.x;
  const int lane = tid & 63, wid = tid >> 6;
  const int quad = lane >> 4, l16 = lane & 15;
  const int wm = wid >> 1, wn = wid & 1;  // 2x2 waves, 64x64 each
  const long bm = (long)blockIdx.x * 128;
  const long bn = (long)blockIdx.y * 128;

  // staging: 8 GLL16/step; call c covers rows c*32 + wid*8 + (lane>>3).
  // physical 16B-block scb = lane&7 holds global block scb ^ (row&7),
  // row&7 == lane>>3 (wave-uniform parts are multiples of 8).
  const int srow = wid * 8 + (lane >> 3);
  const int scb = lane & 7;
  const int scbG = scb ^ (lane >> 3);
  const bf16* pa[4]; const bf16* pb[4]; bf16* la[4]; bf16* lb[4];
  #pragma unroll
  for (int c = 0; c < 4; c++) {
    int row = c * 32 + srow;
    pa[c] = A + (bm + row) * (long)K + scbG * 8;
    pb[c] = Bt + (bn + row) * (long)K + scbG * 8;
    la[c] = As + row * 64 + scb * 8;
    lb[c] = Bs + row * 64 + scb * 8;
  }

  const f32x4 zz = {0.f, 0.f, 0.f, 0.f};
  f32x4 acc[4][4];
  #pragma unroll
  for (int i = 0; i < 4; i++)
    #pragma unroll
    for (int j = 0; j < 4; j++) acc[i][j] = zz;

  const int l7 = l16 & 7;  // fragment swizzle key (row&7 == l16&7)
  for (int k0 = 0; k0 < K; k0 += 64) {
    #pragma unroll
    for (int c = 0; c < 4; c++) {
      GLL16(pa[c] + k0, la[c]);
      GLL16(pb[c] + k0, lb[c]);
    }
    __syncthreads();
    #pragma unroll
    for (int ks = 0; ks < 2; ks++) {
      const int fcol = ((ks * 4 + quad) ^ l7) * 8;
      bf16x8 a[4], b[4];
      #pragma unroll
      for (int i = 0; i < 4; i++)
        a[i] = *(const bf16x8*)(As + (wm * 64 + i * 16 + l16) * 64 + fcol);
      #pragma unroll
      for (int j = 0; j < 4; j++)
        b[j] = *(const bf16x8*)(Bs + (wn * 64 + j * 16 + l16) * 64 + fcol);
      #pragma unroll
      for (int i = 0; i < 4; i++)
        #pragma unroll
        for (int j = 0; j < 4; j++)
          acc[i][j] = __builtin_amdgcn_mfma_f32_16x16x32_bf16(a[i], b[j], acc[i][j], 0, 0, 0);
    }
    __syncthreads();
  }

  if constexpr (DO_SWIGLU) {
    // permuted-B layout: j even = gate, j odd = value for the same act col.
    #pragma unroll
    for (int i = 0; i < 4; i++)
      #pragma unroll
      for (int jp = 0; jp < 2; jp++) {
        long acol = bn / 2 + wn * 32 + jp * 16 + l16;
        #pragma unroll
        for (int r = 0; r < 4; r++) {
          long row = bm + wm * 64 + i * 16 + quad * 4 + r;
          float gate = acc[i][2 * jp][r];
          float val = acc[i][2 * jp + 1][r];
          C2[row * 2816 + acol] = f2bf(siluf(gate) * val);
        }
      }
  } else {
    const bool sec = (bn >= split);  // block-uniform
    #pragma unroll
    for (int i = 0; i < 4; i++)
      #pragma unroll
      for (int j = 0; j < 4; j++)
        #pragma unroll
        for (int r = 0; r < 4; r++) {
          long row = bm + wm * 64 + i * 16 + quad * 4 + r;  // C: row=quad*4+r
          long col = bn + wn * 64 + j * 16 + l16;
          float v = acc[i][j][r];
          if (sec) {
            C2[row * 2048 + (col - split)] = f2bf(v);
          } else {
            if constexpr (DO_ADD) v += addend[row * (long)ldc + col];
            if constexpr (std::is_same<OUT_T, float>::value)
              C[row * (long)ldc + col] = v;
            else
              C[row * (long)ldc + col] = f2bf(v);
          }
        }
  }
}

// ---------------------------------------------------------------- conv(K=4)+silu, vectorized; z=0 q(rope,scale) z=1 k(rope) z=2 v
__global__ void conv3(const bf16* __restrict__ u3,
                      const float* __restrict__ cwq, const float* __restrict__ cwk,
                      const float* __restrict__ cwv, const float2* __restrict__ rtab,
                      bf16* __restrict__ qb, bf16* __restrict__ kb,
                      bf16* __restrict__ vb) {
  const int bt = blockIdx.x;
  const int t = bt & 2047;
  const int b = bt >> 11;
  const int z = blockIdx.y;
  const int tid = threadIdx.x;  // 256
  const int h = tid >> 5;
  if (z < 2) {  // q/k: conv + silu + rope, 4 (j, j+128) pairs per thread
    const float* cw = z == 0 ? cwq : cwk;
    bf16* out = z == 0 ? qb : kb;
    const float scale = z == 0 ? 0.0625f : 1.0f;  // dk^-0.5 folded into q
    const int j0 = (tid & 31) * 4;
    const int ch1 = h * 256 + j0, ch2 = ch1 + 128;
    const int c1 = z * 2048 + ch1, c2 = c1 + 128;
    f32x4 w1[4], w2[4];
    #pragma unroll
    for (int e = 0; e < 4; e++) {
      w1[e] = *(const f32x4*)(cw + (ch1 + e) * 4);
      w2[e] = *(const f32x4*)(cw + (ch2 + e) * 4);
    }
    float a1[4] = {0.f, 0.f, 0.f, 0.f}, a2[4] = {0.f, 0.f, 0.f, 0.f};
    #pragma unroll
    for (int i = 0; i < 4; i++) {
      int ts = t - 3 + i;
      if (ts >= 0) {
        const bf16* up = u3 + (long)(bt - 3 + i) * 6144;
        bf16x4 v1 = *(const bf16x4*)(up + c1);
        bf16x4 v2 = *(const bf16x4*)(up + c2);
        #pragma unroll
        for (int e = 0; e < 4; e++) {
          a1[e] += (float)v1[e] * w1[e][i];
          a2[e] += (float)v2[e] * w2[e][i];
        }
      }
    }
    f32x4 r01 = *(const f32x4*)(rtab + t * 128 + j0);
    f32x4 r23 = *(const f32x4*)(rtab + t * 128 + j0 + 2);
    float cs[4] = {r01[0], r01[2], r23[0], r23[2]};
    float sn[4] = {r01[1], r01[3], r23[1], r23[3]};
    bf16x4 o1, o2;
    #pragma unroll
    for (int e = 0; e < 4; e++) {
      float s1 = siluf(a1[e]), s2 = siluf(a2[e]);
      o1[e] = (__bf16)((s1 * cs[e] - s2 * sn[e]) * scale);
      o2[e] = (__bf16)((s2 * cs[e] + s1 * sn[e]) * scale);
    }
    long obase = ((long)(b * 8 + h) * 2048 + t) * 256;
    *(bf16x4*)(out + obase + j0) = o1;
    *(bf16x4*)(out + obase + 128 + j0) = o2;
  } else {  // v: conv + silu, 8 contiguous per thread
    const int e0 = (tid & 31) * 8;
    const int ch = h * 256 + e0;
    const int c = 4096 + ch;
    f32x4 w[8];
    #pragma unroll
    for (int e = 0; e < 8; e++) w[e] = *(const f32x4*)(cwv + (ch + e) * 4);
    float a[8] = {0.f, 0.f, 0.f, 0.f, 0.f, 0.f, 0.f, 0.f};
    #pragma unroll
    for (int i = 0; i < 4; i++) {
      int ts = t - 3 + i;
      if (ts >= 0) {
        bf16x8 v = *(const bf16x8*)(u3 + (long)(bt - 3 + i) * 6144 + c);
        #pragma unroll
        for (int e = 0; e < 8; e++) a[e] += (float)v[e] * w[e][i];
      }
    }
    bf16x8 o;
    #pragma unroll
    for (int e = 0; e < 8; e++) o[e] = (__bf16)siluf(a[e]);
    *(bf16x8*)(vb + ((long)(b * 8 + h) * 2048 + t) * 256 + e0) = o;
  }
}

// ---------------------------------------------------------------- retention A: per (bh,chunk) M^T[e][d] = sum_t v[t,e]*k'[t,d]
__global__ __launch_bounds__(256) void chunk_outer(
    const bf16* __restrict__ vT, const bf16* __restrict__ kTd,
    bf16* __restrict__ states) {
  __shared__ alignas(16) bf16 lk[256 * 72];
  const int chunk = blockIdx.x, bh = blockIdx.y;
  const int tid = threadIdx.x;
  const int lane = tid & 63, wid = tid >> 6;
  const int quad = lane >> 4, l16 = lane & 15;
  const long base = (long)bh * 256 * 2048 + chunk * 64;

  #pragma unroll
  for (int it = 0; it < 8; it++) {
    int r = it * 32 + (tid >> 3);
    int cb = tid & 7;
    *(int4*)(lk + r * 72 + cb * 8) = *(const int4*)(kTd + base + (long)r * 2048 + cb * 8);
  }
  bf16x8 a[4][2];
  #pragma unroll
  for (int i = 0; i < 4; i++)
    #pragma unroll
    for (int ks = 0; ks < 2; ks++)
      a[i][ks] = *(const bf16x8*)(vT + base + (long)(wid * 64 + i * 16 + l16) * 2048 +
                                  ks * 32 + quad * 8);
  __syncthreads();

  bf16* sout = states + ((long)bh * 32 + chunk) * 65536;
  const f32x4 zz = {0.f, 0.f, 0.f, 0.f};
  for (int g = 0; g < 4; g++) {
    f32x4 acc[4][4];
    #pragma unroll
    for (int i = 0; i < 4; i++)
      #pragma unroll
      for (int j = 0; j < 4; j++) acc[i][j] = zz;
    #pragma unroll
    for (int ks = 0; ks < 2; ks++) {
      bf16x8 b[4];
      #pragma unroll
      for (int j = 0; j < 4; j++)
        b[j] = *(const bf16x8*)(lk + (g * 64 + j * 16 + l16) * 72 + ks * 32 + quad * 8);
      #pragma unroll
      for (int i = 0; i < 4; i++)
        #pragma unroll
        for (int j = 0; j < 4; j++)
          acc[i][j] = __builtin_amdgcn_mfma_f32_16x16x32_bf16(a[i][ks], b[j], acc[i][j], 0, 0, 0);
    }
    #pragma unroll
    for (int i = 0; i < 4; i++)
      #pragma unroll
      for (int j = 0; j < 4; j++)
        #pragma unroll
        for (int r = 0; r < 4; r++) {
          int e = wid * 64 + i * 16 + quad * 4 + r;
          int d = g * 64 + j * 16 + l16;
          sout[(long)e * 256 + d] = f2bf(acc[i][j][r]);
        }
  }
}

// ---------------------------------------------------------------- retention B: in-place decay scan, 8 elems/thread (vectorized)
__global__ void state_scan(bf16* __restrict__ states) {
  const int bh = blockIdx.y, h = bh & 7;
  const float gC = exp2f(64.f * log2gamma(h));
  long idx = ((long)blockIdx.x * 256 + threadIdx.x) * 8;  // grid.x=32 -> 65536
  bf16* p = states + (long)bh * 32 * 65536 + idx;
  float s[8] = {0.f, 0.f, 0.f, 0.f, 0.f, 0.f, 0.f, 0.f};
  for (int n = 0; n < 32; n++) {
    bf16x8 m = *(const bf16x8*)(p + (long)n * 65536);
    bf16x8 o;
    #pragma unroll
    for (int e = 0; e < 8; e++) {
      o[e] = (__bf16)s[e];
      s[e] = gC * s[e] + (float)m[e];
    }
    *(bf16x8*)(p + (long)n * 65536) = o;
  }
}

// ---------------------------------------------------------------- retention C: O = [A*Dm | q*di] @ [v ; S], fused gated rmsnorm
__global__ __launch_bounds__(256) void chunk_inner(
    const bf16* __restrict__ q, const bf16* __restrict__ k,
    const bf16* __restrict__ vT, const bf16* __restrict__ ST,
    const bf16* __restrict__ g, const float* __restrict__ gw,
    bf16* __restrict__ og) {
  __shared__ alignas(16) bf16 P[64 * 328];
  __shared__ float sq[64][4];
  __shared__ float sscale[64];
  const int chunk = blockIdx.x, bh = blockIdx.y;
  const int b_ = bh >> 3, h = bh & 7;
  const float lg = log2gamma(h);
  const int tid = threadIdx.x;
  const int lane = tid & 63, wid = tid >> 6;
  const int quad = lane >> 4, l16 = lane & 15;
  const long qkbase = ((long)bh * 2048 + chunk * 64) * 256;

  {  // P-right: q * di, di = gamma^(row+1)
    const int row = tid >> 2, cb = tid & 3;
    const float di = exp2f(lg * (float)(row + 1));
    const bf16* qs = q + qkbase + (long)row * 256 + cb * 64;
    bf16* pd = P + row * 328 + 64 + cb * 64;
    #pragma unroll
    for (int mb = 0; mb < 8; mb++) {
      bf16x8 v = *(const bf16x8*)(qs + mb * 8);
      #pragma unroll
      for (int e = 0; e < 8; e++) pd[mb * 8 + e] = f2bf((float)v[e] * di);
    }
  }

  {  // A = q k^T with decay mask -> P-left
    const f32x4 zz = {0.f, 0.f, 0.f, 0.f};
    f32x4 acc[4];
    #pragma unroll
    for (int j = 0; j < 4; j++) acc[j] = zz;
    #pragma unroll
    for (int ks = 0; ks < 8; ks++) {
      bf16x8 a = *(const bf16x8*)(q + qkbase + (long)(wid * 16 + l16) * 256 + ks * 32 + quad * 8);
      #pragma unroll
      for (int j = 0; j < 4; j++) {
        bf16x8 b = *(const bf16x8*)(k + qkbase + (long)(j * 16 + l16) * 256 + ks * 32 + quad * 8);
        acc[j] = __builtin_amdgcn_mfma_f32_16x16x32_bf16(a, b, acc[j], 0, 0, 0);
      }
    }
    #pragma unroll
    for (int j = 0; j < 4; j++)
      #pragma unroll
      for (int r = 0; r < 4; r++) {
        int il = wid * 16 + quad * 4 + r;
        int jl = j * 16 + l16;
        int dd = il - jl;
        float v = (dd >= 0) ? acc[j][r] * exp2f(lg * (float)dd) : 0.f;
        P[il * 328 + jl] = f2bf(v);
      }
  }
  __syncthreads();

  // O = P @ [v ; S]
  const f32x4 zz = {0.f, 0.f, 0.f, 0.f};
  f32x4 acc[4][4];
  #pragma unroll
  for (int i = 0; i < 4; i++)
    #pragma unroll
    for (int j = 0; j < 4; j++) acc[i][j] = zz;
  const long vbase = (long)bh * 256 * 2048 + chunk * 64;
  const long sbase = ((long)bh * 32 + chunk) * 65536;
  #pragma unroll
  for (int ks = 0; ks < 10; ks++) {
    bf16x8 a[4];
    #pragma unroll
    for (int i = 0; i < 4; i++)
      a[i] = *(const bf16x8*)(P + (i * 16 + l16) * 328 + ks * 32 + quad * 8);
    int kk = ks * 32 + quad * 8;
    bf16x8 b[4];
    #pragma unroll
    for (int j = 0; j < 4; j++) {
      int e = wid * 64 + j * 16 + l16;
      const bf16* src = (kk < 64) ? (vT + vbase + (long)e * 2048 + kk)
                                  : (ST + sbase + (long)e * 256 + (kk - 64));
      b[j] = *(const bf16x8*)src;
    }
    #pragma unroll
    for (int i = 0; i < 4; i++)
      #pragma unroll
      for (int j = 0; j < 4; j++)
        acc[i][j] = __builtin_amdgcn_mfma_f32_16x16x32_bf16(a[i], b[j], acc[i][j], 0, 0, 0);
  }

  // fused rmsnorm(o) * gw * silu(g)
  #pragma unroll
  for (int i = 0; i < 4; i++)
    #pragma unroll
    for (int r = 0; r < 4; r++) {
      float s = acc[i][0][r]*acc[i][0][r] + acc[i][1][r]*acc[i][1][r]
              + acc[i][2][r]*acc[i][2][r] + acc[i][3][r]*acc[i][3][r];
      s += __shfl_xor(s, 1, 64);
      s += __shfl_xor(s, 2, 64);
      s += __shfl_xor(s, 4, 64);
      s += __shfl_xor(s, 8, 64);
      if (l16 == 0) sq[i * 16 + quad * 4 + r][wid] = s;
    }
  __syncthreads();
  if (tid < 64) {
    float t = sq[tid][0] + sq[tid][1] + sq[tid][2] + sq[tid][3];
    sscale[tid] = rsqrtf(t * (1.f/256.f) + 1e-5f);
  }
  __syncthreads();

  #pragma unroll
  for (int i = 0; i < 4; i++)
    #pragma unroll
    for (int j = 0; j < 4; j++) {
      int e = wid * 64 + j * 16 + l16;
      float w = gw[e];
      #pragma unroll
      for (int r = 0; r < 4; r++) {
        int row = i * 16 + quad * 4 + r;
        long bt = (long)b_ * 2048 + chunk * 64 + row;
        float gg = bf2f(g[bt * 2048 + h * 256 + e]);
        float val = acc[i][j][r] * sscale[row] * w * siluf(gg);
        og[bt * 2048 + h * 256 + e] = f2bf(val);
      }
    }
}

// ================================================================ launch
extern "C" void kernel_launch(void* const* d_in, const int* in_sizes, int n_in,
                              void* d_out, int out_size, void* d_ws, size_t ws_size,
                              hipStream_t stream) {
  (void)in_sizes; (void)n_in; (void)out_size;
  const float* hidden = (const float*)d_in[0];
  const float* attn_w = (const float*)d_in[1];
  const float* Wq = (const float*)d_in[2];
  const float* Wk = (const float*)d_in[3];
  const float* Wv = (const float*)d_in[4];
  const float* Wg = (const float*)d_in[5];
  const float* Wo = (const float*)d_in[6];
  const float* cwq = (const float*)d_in[7];
  const float* cwk = (const float*)d_in[8];
  const float* cwv = (const float*)d_in[9];
  const float* gnw = (const float*)d_in[10];
  const float* mlpw = (const float*)d_in[11];
  const float* Wgate = (const float*)d_in[12];
  const float* Wdown = (const float*)d_in[13];
  float* out = (float*)d_out;
  char* ws = (char*)d_ws;

  if (ws_size < 209715200ull) return;  // guard (known-good)

  // ---- workspace layout, 186.6 MB, liveness-verified aliasing:
  // WTr [0,33.55M): WT4 | per-GEMM weight buffers (seq reuse); og @+16.78M
  // Ur  [33.55,100.66M): u3+xbf -> states -> hbuf; act @+33.55M
  // Qr  [100.66,167.77M): qb|kb|vTb|vnb; ybf @+50.33M (over vnb, dead)
  // g   [167.77,184.55M); rtab [184.55,186.65M)
  const size_t MB16 = 16777216ull;
  char* WTr = ws;
  bf16* WT4    = (bf16*)WTr;
  bf16* kTb    = (bf16*)WTr;
  bf16* WoT    = (bf16*)WTr;
  bf16* WgateT = (bf16*)WTr;
  bf16* WdownT = (bf16*)WTr;
  bf16* og     = (bf16*)(WTr + MB16);
  char* Ur = ws + 33554432ull;
  bf16*  u3     = (bf16*)Ur;
  bf16*  xbf    = (bf16*)(Ur + 50331648ull);
  bf16*  states = (bf16*)Ur;
  float* hbuf   = (float*)Ur;
  bf16*  act    = (bf16*)(Ur + 33554432ull);
  char* Qr = ws + 100663296ull;
  bf16* qb  = (bf16*)Qr;
  bf16* kb  = (bf16*)(Qr + MB16);
  bf16* vTb = (bf16*)(Qr + 2 * MB16);
  bf16* vnb = (bf16*)(Qr + 3 * MB16);
  bf16* ybf = (bf16*)(Qr + 50331648ull);
  bf16* g   = (bf16*)(ws + 167772160ull);
  float2* rtab = (float2*)(ws + 184549376ull);

  dim3 tb32(32, 8);

  rope_init<<<2048, 128, 0, stream>>>(rtab);
  rmsnorm_k<<<4096, 256, 0, stream>>>(hidden, attn_w, xbf);

  // merged QKVG projection: N=8192, qkv cols -> u3 (ldc 6144), g cols -> g
  transpose_w4<<<dim3(64, 64, 4), tb32, 0, stream>>>(Wq, Wk, Wv, Wg, WT4);
  gemm_bt<bf16, false, false><<<dim3(32, 64), 256, 0, stream>>>(
      xbf, WT4, u3, 6144, g, 6144, nullptr, 4096, 8192, 2048);

  // conv + silu (+rope) for q/k/v in one launch (vectorized)
  conv3<<<dim3(4096, 3), 256, 0, stream>>>(u3, cwq, cwk, cwv, rtab, qb, kb, vnb);
  transpose_head<<<dim3(8, 64, 16), tb32, 0, stream>>>(kb, kTb, 1);  // fold dkc
  transpose_head<<<dim3(8, 64, 16), tb32, 0, stream>>>(vnb, vTb, 0);

  // retention (states overwrite u3+xbf — both dead here)
  chunk_outer<<<dim3(32, 16), 256, 0, stream>>>(vTb, kTb, states);
  state_scan<<<dim3(32, 16), 256, 0, stream>>>(states);
  chunk_inner<<<dim3(32, 16), 256, 0, stream>>>(qb, kb, vTb, states, g, gnw, og);

  // output projection + residual (states dead -> hbuf region free)
  transpose_w<<<dim3(64, 64), tb32, 0, stream>>>(Wo, WoT, 2048, 2048);
  gemm_bt<float, true, false><<<dim3(32, 16), 256, 0, stream>>>(
      og, WoT, hbuf, 2048, nullptr, 1 << 30, hidden, 4096, 2048, 2048);

  // MLP: rmsnorm -> W_gate GEMM with fused swiglu (permuted B) -> W_down
  rmsnorm_k<<<4096, 256, 0, stream>>>(hbuf, mlpw, ybf);
  transpose_wgate<<<dim3(176, 64), tb32, 0, stream>>>(Wgate, WgateT);
  gemm_bt<bf16, false, true><<<dim3(32, 44), 256, 0, stream>>>(
      ybf, WgateT, nullptr, 2816, act, 1 << 30, nullptr, 4096, 5632, 2048);
  transpose_w<<<dim3(64, 88), tb32, 0, stream>>>(Wdown, WdownT, 2816, 2048);
  gemm_bt<float, true, false><<<dim3(32, 16), 256, 0, stream>>>(
      act, WdownT, out, 2048, nullptr, 1 << 30, hbuf, 4096, 2048, 2816);
}